// Round 1
// baseline (17328.764 us; speedup 1.0000x reference)
//
#include <hip/hip_runtime.h>
#include <hip/hip_cooperative_groups.h>

namespace cg = cooperative_groups;

#define DD 1536
#define TT 512
#define BB 64
#define BD (BB*DD)      /* 98304 */
#define TBD (TT*BD)     /* 50331648 */

typedef __attribute__((ext_vector_type(8))) short short8;
typedef __attribute__((ext_vector_type(4))) short short4v;
typedef __attribute__((ext_vector_type(4))) float f32x4;

__device__ __forceinline__ short f2bf(float f) {
  unsigned u = __builtin_bit_cast(unsigned, f);
  u += 0x7FFFu + ((u >> 16) & 1u);   // RNE
  return (short)(u >> 16);
}

// ---------------- power iteration helpers (f32 exact) ----------------

// y[i] = sum_j W[i,j] x[j]   (one wave per row)
__global__ __launch_bounds__(256) void k_matvec_row(
    const float* __restrict__ W, const float* __restrict__ x, float* __restrict__ y) {
  int wave = (blockIdx.x * 256 + threadIdx.x) >> 6;
  int lane = threadIdx.x & 63;
  const float* Wr = W + (size_t)wave * DD;
  float acc = 0.f;
  for (int j = lane; j < DD; j += 64) acc += Wr[j] * x[j];
  for (int off = 32; off; off >>= 1) acc += __shfl_down(acc, off, 64);
  if (lane == 0) y[wave] = acc;
}

// y[j] += partial of sum_i W[i,j] x[i]  (y pre-zeroed; grid = (6 j-tiles, 8 i-chunks))
__global__ __launch_bounds__(256) void k_matvec_col(
    const float* __restrict__ W, const float* __restrict__ x, float* __restrict__ y) {
  int j = blockIdx.x * 256 + threadIdx.x;
  int i0 = blockIdx.y * 192;
  float acc = 0.f;
  for (int i = i0; i < i0 + 192; ++i) acc += W[(size_t)i * DD + j] * x[i];
  atomicAdd(&y[j], acc);
}

// s = sigmoid(log_radius)*0.999 / (||t6||/||t5|| + 1e-8)
__global__ __launch_bounds__(256) void k_scale(
    const float* __restrict__ t5, const float* __restrict__ t6,
    const float* __restrict__ log_radius, float* __restrict__ s_out) {
  __shared__ float red[8];
  int tid = threadIdx.x;
  float a5 = 0.f, a6 = 0.f;
  for (int i = tid; i < DD; i += 256) { float v5 = t5[i], v6 = t6[i]; a5 += v5*v5; a6 += v6*v6; }
  for (int off = 32; off; off >>= 1) { a5 += __shfl_down(a5, off, 64); a6 += __shfl_down(a6, off, 64); }
  int w = tid >> 6, lane = tid & 63;
  if (lane == 0) { red[w] = a5; red[4 + w] = a6; }
  __syncthreads();
  if (tid == 0) {
    float s5 = red[0] + red[1] + red[2] + red[3];
    float s6 = red[4] + red[5] + red[6] + red[7];
    float sigma = sqrtf(s6 / s5);
    float lr = log_radius[0];
    float target = 0.999f / (1.f + expf(-lr));
    s_out[0] = target / (sigma + 1e-8f);
  }
}

// ---------------- phase 1: A = x @ Wx^T + b  -> d_out[outs region] ----------------
// 128x128 tile, BK=64, bf16 MFMA, reg-staged (f32 -> bf16 cvt in staging), XOR-swizzled LDS.
__global__ __launch_bounds__(256) void k_gemm_xA(
    const float* __restrict__ x, const float* __restrict__ Wx,
    const float* __restrict__ bias, float* __restrict__ Aout) {
  __shared__ short As[128 * 64];
  __shared__ short Bs[128 * 64];
  const int tid = threadIdx.x;
  const int lane = tid & 63;
  const int w = tid >> 6;
  const int n0 = blockIdx.x * 128;
  const int m0 = blockIdx.y * 128;
  const int mq = (w >> 1) * 64;
  const int nq = (w & 1) * 64;

  f32x4 acc[4][4];
#pragma unroll
  for (int i = 0; i < 4; ++i)
#pragma unroll
    for (int j = 0; j < 4; ++j) acc[i][j] = (f32x4){0.f, 0.f, 0.f, 0.f};

  const int r0 = tid >> 3;     // staging: row = c*32 + r0, 8 chunks of 8 bf16 per row
  const int c8 = tid & 7;

  for (int k0 = 0; k0 < DD; k0 += 64) {
    __syncthreads();
#pragma unroll
    for (int c = 0; c < 4; ++c) {
      int row = c * 32 + r0;
      const float4* gx = (const float4*)(x + (size_t)(m0 + row) * DD + k0 + c8 * 8);
      const float4* gw = (const float4*)(Wx + (size_t)(n0 + row) * DD + k0 + c8 * 8);
      float4 x0 = gx[0], x1 = gx[1];
      float4 w0 = gw[0], w1 = gw[1];
      short8 xv, wv;
      xv[0]=f2bf(x0.x); xv[1]=f2bf(x0.y); xv[2]=f2bf(x0.z); xv[3]=f2bf(x0.w);
      xv[4]=f2bf(x1.x); xv[5]=f2bf(x1.y); xv[6]=f2bf(x1.z); xv[7]=f2bf(x1.w);
      wv[0]=f2bf(w0.x); wv[1]=f2bf(w0.y); wv[2]=f2bf(w0.z); wv[3]=f2bf(w0.w);
      wv[4]=f2bf(w1.x); wv[5]=f2bf(w1.y); wv[6]=f2bf(w1.z); wv[7]=f2bf(w1.w);
      int so = (row * 64 + c8 * 8) ^ ((row & 7) << 3);
      *(short8*)&As[so] = xv;
      *(short8*)&Bs[so] = wv;
    }
    __syncthreads();
#pragma unroll
    for (int kk = 0; kk < 64; kk += 32) {
      short8 af[4], bfr[4];
#pragma unroll
      for (int f = 0; f < 4; ++f) {
        int ar = mq + f * 16 + (lane & 15);
        int k = kk + ((lane >> 4) << 3);
        af[f] = *(const short8*)&As[(ar * 64 + k) ^ ((ar & 7) << 3)];
        int br = nq + f * 16 + (lane & 15);
        bfr[f] = *(const short8*)&Bs[(br * 64 + k) ^ ((br & 7) << 3)];
      }
#pragma unroll
      for (int i = 0; i < 4; ++i)
#pragma unroll
        for (int j = 0; j < 4; ++j)
          acc[i][j] = __builtin_amdgcn_mfma_f32_16x16x32_bf16(af[i], bfr[j], acc[i][j], 0, 0, 0);
    }
  }
#pragma unroll
  for (int i = 0; i < 4; ++i) {
    int rbase = m0 + mq + i * 16 + ((lane >> 4) << 2);
#pragma unroll
    for (int j = 0; j < 4; ++j) {
      int col = n0 + nq + j * 16 + (lane & 15);
      float bv = bias[col];
#pragma unroll
      for (int r = 0; r < 4; ++r)
        Aout[(size_t)(rbase + r) * DD + col] = acc[i][j][r] + bv;
    }
  }
}

// ---------------- phase 2: sequential recurrence (cooperative) ----------------
// 96 WGs x 256 thr. WG owns 16 output features; Wh slice resident in LDS (bf16, swizzled).
// Per step: acc = h_prev @ Wh_slice^T (a-frags direct from L2), epilogue fuses
// tanh, h_all write, outs = h*silu(z) (overwriting A in-place), bf16 h for next step.
__global__ __launch_bounds__(256) void k_recur(
    const float* __restrict__ Wh, const float* __restrict__ h0,
    const float* __restrict__ z, const float* __restrict__ sp,
    float* __restrict__ outs, float* __restrict__ hall,
    short* __restrict__ hb0, short* __restrict__ hb1) {
  __shared__ short WhS[16 * DD];   // 48 KB
  cg::grid_group grid = cg::this_grid();
  const int tid = threadIdx.x;
  const int lane = tid & 63;
  const int w = tid >> 6;
  const int n0 = blockIdx.x * 16;

  // load Wh slice -> LDS bf16, swizzled: 16 rows x 1536
#pragma unroll
  for (int c = 0; c < 12; ++c) {
    int idx = c * 256 + tid;          // 0..3071
    int row = idx / 192;
    int cc = idx - row * 192;         // 0..191 (chunks of 8)
    const float4* g = (const float4*)(Wh + (size_t)(n0 + row) * DD + cc * 8);
    float4 a0 = g[0], a1 = g[1];
    short8 v;
    v[0]=f2bf(a0.x); v[1]=f2bf(a0.y); v[2]=f2bf(a0.z); v[3]=f2bf(a0.w);
    v[4]=f2bf(a1.x); v[5]=f2bf(a1.y); v[6]=f2bf(a1.z); v[7]=f2bf(a1.w);
    int so = (row * DD + cc * 8) ^ ((row & 7) << 3);
    *(short8*)&WhS[so] = v;
  }
  // init: h_all[0] = h0 (f32), hb0 = bf16(h0)
  {
    int base = (blockIdx.x * 256 + tid) * 4;
    float4 v = *(const float4*)(h0 + base);
    *(float4*)(hall + base) = v;
    short4v hv;
    hv[0]=f2bf(v.x); hv[1]=f2bf(v.y); hv[2]=f2bf(v.z); hv[3]=f2bf(v.w);
    *(short4v*)(hb0 + base) = hv;
  }
  const float sv = sp[0];
  __threadfence();
  grid.sync();

  const int nl = lane & 15;
  const int hi8 = (lane >> 4) << 3;
  const int bRow = nl * DD;
  const int bSwz = (nl & 7) << 3;
  const int mrow = w * 16 + nl;
  const int col = n0 + nl;
  const int mb = w * 16 + ((lane >> 4) << 2);

  for (int t = 0; t < TT; ++t) {
    const short* __restrict__ Hg = (t & 1) ? hb1 : hb0;
    short* __restrict__ Hn = (t & 1) ? hb0 : hb1;
    const short* hrow = Hg + (size_t)mrow * DD + hi8;

    f32x4 v0 = (f32x4){0,0,0,0}, v1 = (f32x4){0,0,0,0};
    f32x4 v2 = (f32x4){0,0,0,0}, v3 = (f32x4){0,0,0,0};
#pragma unroll 4
    for (int c = 0; c < 48; c += 4) {
      short8 aa0 = *(const short8*)(hrow + (c + 0) * 32);
      short8 bb0 = *(const short8*)&WhS[(bRow + (c + 0) * 32 + hi8) ^ bSwz];
      v0 = __builtin_amdgcn_mfma_f32_16x16x32_bf16(aa0, bb0, v0, 0, 0, 0);
      short8 aa1 = *(const short8*)(hrow + (c + 1) * 32);
      short8 bb1 = *(const short8*)&WhS[(bRow + (c + 1) * 32 + hi8) ^ bSwz];
      v1 = __builtin_amdgcn_mfma_f32_16x16x32_bf16(aa1, bb1, v1, 0, 0, 0);
      short8 aa2 = *(const short8*)(hrow + (c + 2) * 32);
      short8 bb2 = *(const short8*)&WhS[(bRow + (c + 2) * 32 + hi8) ^ bSwz];
      v2 = __builtin_amdgcn_mfma_f32_16x16x32_bf16(aa2, bb2, v2, 0, 0, 0);
      short8 aa3 = *(const short8*)(hrow + (c + 3) * 32);
      short8 bb3 = *(const short8*)&WhS[(bRow + (c + 3) * 32 + hi8) ^ bSwz];
      v3 = __builtin_amdgcn_mfma_f32_16x16x32_bf16(aa3, bb3, v3, 0, 0, 0);
    }
    f32x4 accS = (v0 + v1) + (v2 + v3);

    size_t tb = (size_t)t * BD;
#pragma unroll
    for (int r = 0; r < 4; ++r) {
      int m = mb + r;
      size_t gi = tb + (size_t)m * DD + col;
      float pre = outs[gi] + sv * accS[r];   // outs holds A = x@Wx^T + b here
      float h = tanhf(pre);
      hall[tb + BD + (size_t)m * DD + col] = h;
      float zz = z[gi];
      outs[gi] = h * (zz / (1.f + __expf(-zz)));   // silu
      Hn[(size_t)m * DD + col] = f2bf(h);
    }
    __threadfence();
    grid.sync();
  }
}

// ---------------- launcher ----------------
extern "C" void kernel_launch(void* const* d_in, const int* in_sizes, int n_in,
                              void* d_out, int out_size, void* d_ws, size_t ws_size,
                              hipStream_t stream) {
  const float* x  = (const float*)d_in[0];
  const float* z  = (const float*)d_in[1];
  const float* h0 = (const float*)d_in[2];
  const float* Wx = (const float*)d_in[3];
  const float* Wh = (const float*)d_in[4];
  const float* b  = (const float*)d_in[5];
  const float* lr = (const float*)d_in[6];
  const float* u  = (const float*)d_in[7];

  float* outs = (float*)d_out;            // holds A first, then outs
  float* hall = outs + (size_t)TBD;

  char* ws = (char*)d_ws;
  float* vA = (float*)ws;                 // 1536
  float* vB = vA + DD;
  float* vC = vB + DD;
  float* vD = vC + DD;
  float* sS = vD + DD;                    // 1 scalar
  short* hb0 = (short*)(ws + 32768);      // [B,D] bf16 ping
  short* hb1 = hb0 + BD;                  // pong

  // phase 1: big GEMM (independent; enqueue first)
  hipLaunchKernelGGL(k_gemm_xA, dim3(12, 256), dim3(256), 0, stream, x, Wx, b, outs);

  // phase 0: power iteration (6 unnormalized matvecs + norm ratio)
  hipMemsetAsync(vA, 0, DD * sizeof(float), stream);
  hipLaunchKernelGGL(k_matvec_col, dim3(6, 8), dim3(256), 0, stream, Wh, u, vA);   // t1 = W^T u
  hipLaunchKernelGGL(k_matvec_row, dim3(384), dim3(256), 0, stream, Wh, vA, vB);   // t2 = W t1
  hipMemsetAsync(vA, 0, DD * sizeof(float), stream);
  hipLaunchKernelGGL(k_matvec_col, dim3(6, 8), dim3(256), 0, stream, Wh, vB, vA);  // t3 = W^T t2
  hipLaunchKernelGGL(k_matvec_row, dim3(384), dim3(256), 0, stream, Wh, vA, vB);   // t4 = W t3
  hipMemsetAsync(vC, 0, DD * sizeof(float), stream);
  hipLaunchKernelGGL(k_matvec_col, dim3(6, 8), dim3(256), 0, stream, Wh, vB, vC);  // t5 = W^T t4
  hipLaunchKernelGGL(k_matvec_row, dim3(384), dim3(256), 0, stream, Wh, vC, vD);   // t6 = W t5
  hipLaunchKernelGGL(k_scale, dim3(1), dim3(256), 0, stream, vC, vD, lr, sS);

  // phase 2: cooperative recurrence
  void* args[8] = {(void*)&Wh, (void*)&h0, (void*)&z, (void*)&sS,
                   (void*)&outs, (void*)&hall, (void*)&hb0, (void*)&hb1};
  hipLaunchCooperativeKernel((const void*)k_recur, dim3(96), dim3(256), args, 0, stream);
}

// Round 2
// 13376.270 us; speedup vs baseline: 1.2955x; 1.2955x over previous
//
#include <hip/hip_runtime.h>

#define DD 1536
#define TT 512
#define BB 64
#define BD (BB*DD)      /* 98304 */
#define TBD (TT*BD)     /* 50331648 */
#define NWG 96

typedef __attribute__((ext_vector_type(8))) short short8;
typedef __attribute__((ext_vector_type(4))) short short4v;
typedef __attribute__((ext_vector_type(4))) float f32x4;

__device__ __forceinline__ short f2bf(float f) {
  unsigned u = __builtin_bit_cast(unsigned, f);
  u += 0x7FFFu + ((u >> 16) & 1u);   // RNE
  return (short)(u >> 16);
}

// ---------------- power iteration helpers (f32 exact) ----------------

__global__ __launch_bounds__(256) void k_matvec_row(
    const float* __restrict__ W, const float* __restrict__ x, float* __restrict__ y) {
  int wave = (blockIdx.x * 256 + threadIdx.x) >> 6;
  int lane = threadIdx.x & 63;
  const float* Wr = W + (size_t)wave * DD;
  float acc = 0.f;
  for (int j = lane; j < DD; j += 64) acc += Wr[j] * x[j];
  for (int off = 32; off; off >>= 1) acc += __shfl_down(acc, off, 64);
  if (lane == 0) y[wave] = acc;
}

__global__ __launch_bounds__(256) void k_matvec_col(
    const float* __restrict__ W, const float* __restrict__ x, float* __restrict__ y) {
  int j = blockIdx.x * 256 + threadIdx.x;
  int i0 = blockIdx.y * 192;
  float acc = 0.f;
  for (int i = i0; i < i0 + 192; ++i) acc += W[(size_t)i * DD + j] * x[i];
  atomicAdd(&y[j], acc);
}

__global__ __launch_bounds__(256) void k_scale(
    const float* __restrict__ t5, const float* __restrict__ t6,
    const float* __restrict__ log_radius, float* __restrict__ s_out) {
  __shared__ float red[8];
  int tid = threadIdx.x;
  float a5 = 0.f, a6 = 0.f;
  for (int i = tid; i < DD; i += 256) { float v5 = t5[i], v6 = t6[i]; a5 += v5*v5; a6 += v6*v6; }
  for (int off = 32; off; off >>= 1) { a5 += __shfl_down(a5, off, 64); a6 += __shfl_down(a6, off, 64); }
  int w = tid >> 6, lane = tid & 63;
  if (lane == 0) { red[w] = a5; red[4 + w] = a6; }
  __syncthreads();
  if (tid == 0) {
    float s5 = red[0] + red[1] + red[2] + red[3];
    float s6 = red[4] + red[5] + red[6] + red[7];
    float sigma = sqrtf(s6 / s5);
    float lr = log_radius[0];
    float target = 0.999f / (1.f + expf(-lr));
    s_out[0] = target / (sigma + 1e-8f);
  }
}

// ---------------- phase 1: A = x @ Wx^T + b -> d_out[outs region] ----------------
__global__ __launch_bounds__(256) void k_gemm_xA(
    const float* __restrict__ x, const float* __restrict__ Wx,
    const float* __restrict__ bias, float* __restrict__ Aout) {
  __shared__ short As[128 * 64];
  __shared__ short Bs[128 * 64];
  const int tid = threadIdx.x;
  const int lane = tid & 63;
  const int w = tid >> 6;
  const int n0 = blockIdx.x * 128;
  const int m0 = blockIdx.y * 128;
  const int mq = (w >> 1) * 64;
  const int nq = (w & 1) * 64;

  f32x4 acc[4][4];
#pragma unroll
  for (int i = 0; i < 4; ++i)
#pragma unroll
    for (int j = 0; j < 4; ++j) acc[i][j] = (f32x4){0.f, 0.f, 0.f, 0.f};

  const int r0 = tid >> 3;
  const int c8 = tid & 7;

  for (int k0 = 0; k0 < DD; k0 += 64) {
    __syncthreads();
#pragma unroll
    for (int c = 0; c < 4; ++c) {
      int row = c * 32 + r0;
      const float4* gx = (const float4*)(x + (size_t)(m0 + row) * DD + k0 + c8 * 8);
      const float4* gw = (const float4*)(Wx + (size_t)(n0 + row) * DD + k0 + c8 * 8);
      float4 x0 = gx[0], x1 = gx[1];
      float4 w0 = gw[0], w1 = gw[1];
      short8 xv, wv;
      xv[0]=f2bf(x0.x); xv[1]=f2bf(x0.y); xv[2]=f2bf(x0.z); xv[3]=f2bf(x0.w);
      xv[4]=f2bf(x1.x); xv[5]=f2bf(x1.y); xv[6]=f2bf(x1.z); xv[7]=f2bf(x1.w);
      wv[0]=f2bf(w0.x); wv[1]=f2bf(w0.y); wv[2]=f2bf(w0.z); wv[3]=f2bf(w0.w);
      wv[4]=f2bf(w1.x); wv[5]=f2bf(w1.y); wv[6]=f2bf(w1.z); wv[7]=f2bf(w1.w);
      int so = (row * 64 + c8 * 8) ^ ((row & 7) << 3);
      *(short8*)&As[so] = xv;
      *(short8*)&Bs[so] = wv;
    }
    __syncthreads();
#pragma unroll
    for (int kk = 0; kk < 64; kk += 32) {
      short8 af[4], bfr[4];
#pragma unroll
      for (int f = 0; f < 4; ++f) {
        int ar = mq + f * 16 + (lane & 15);
        int k = kk + ((lane >> 4) << 3);
        af[f] = *(const short8*)&As[(ar * 64 + k) ^ ((ar & 7) << 3)];
        int br = nq + f * 16 + (lane & 15);
        bfr[f] = *(const short8*)&Bs[(br * 64 + k) ^ ((br & 7) << 3)];
      }
#pragma unroll
      for (int i = 0; i < 4; ++i)
#pragma unroll
        for (int j = 0; j < 4; ++j)
          acc[i][j] = __builtin_amdgcn_mfma_f32_16x16x32_bf16(af[i], bfr[j], acc[i][j], 0, 0, 0);
    }
  }
#pragma unroll
  for (int i = 0; i < 4; ++i) {
    int rbase = m0 + mq + i * 16 + ((lane >> 4) << 2);
#pragma unroll
    for (int j = 0; j < 4; ++j) {
      int col = n0 + nq + j * 16 + (lane & 15);
      float bv = bias[col];
#pragma unroll
      for (int r = 0; r < 4; ++r)
        Aout[(size_t)(rbase + r) * DD + col] = acc[i][j][r] + bv;
    }
  }
}

// ---------------- phase 2: sequential recurrence, custom fast barrier ----------------
// Monotonic-counter grid barrier: each barrier b (1-based) waits for *bar >= NWG*b.
// Counter zeroed by hipMemsetAsync each launch. Release: per-thread __threadfence
// (wbl2 drains Hn to coherence point) before tid0's arrival atomicAdd. Acquire:
// per-thread __threadfence (inv) after spin. hall/outs stores + next-step A/z
// prefetch are issued AFTER the arrival so they overlap the spin.
__global__ __launch_bounds__(256) void k_recur(
    const float* __restrict__ Wh, const float* __restrict__ h0,
    const float* __restrict__ z, const float* __restrict__ sp,
    float* __restrict__ outs, float* __restrict__ hall,
    short* __restrict__ hb0, short* __restrict__ hb1, int* __restrict__ bar) {
  __shared__ short WhS[16 * DD];   // 48 KB
  const int tid = threadIdx.x;
  const int lane = tid & 63;
  const int w = tid >> 6;
  const int n0 = blockIdx.x * 16;

  // load Wh slice -> LDS bf16, swizzled
#pragma unroll
  for (int c = 0; c < 12; ++c) {
    int idx = c * 256 + tid;
    int row = idx / 192;
    int cc = idx - row * 192;
    const float4* g = (const float4*)(Wh + (size_t)(n0 + row) * DD + cc * 8);
    float4 a0 = g[0], a1 = g[1];
    short8 v;
    v[0]=f2bf(a0.x); v[1]=f2bf(a0.y); v[2]=f2bf(a0.z); v[3]=f2bf(a0.w);
    v[4]=f2bf(a1.x); v[5]=f2bf(a1.y); v[6]=f2bf(a1.z); v[7]=f2bf(a1.w);
    int so = (row * DD + cc * 8) ^ ((row & 7) << 3);
    *(short8*)&WhS[so] = v;
  }
  // init: h_all[0] = h0 (f32), hb0 = bf16(h0)
  {
    int base = (blockIdx.x * 256 + tid) * 4;
    float4 v = *(const float4*)(h0 + base);
    *(float4*)(hall + base) = v;
    short4v hv;
    hv[0]=f2bf(v.x); hv[1]=f2bf(v.y); hv[2]=f2bf(v.z); hv[3]=f2bf(v.w);
    *(short4v*)(hb0 + base) = hv;
  }
  const float sv = sp[0];

  // ---- initial barrier (bidx = 1) ----
  __threadfence();
  __syncthreads();
  if (tid == 0) {
    atomicAdd(bar, 1);
    while (__hip_atomic_load(bar, __ATOMIC_RELAXED, __HIP_MEMORY_SCOPE_AGENT) < NWG)
      __builtin_amdgcn_s_sleep(2);
  }
  __syncthreads();
  __threadfence();

  const int nl = lane & 15;
  const int hi8 = (lane >> 4) << 3;
  const int bRow = nl * DD;
  const int bSwz = (nl & 7) << 3;
  const int mrow = w * 16 + nl;
  const int col = n0 + nl;
  const int mb = w * 16 + ((lane >> 4) << 2);
  const size_t gbase = (size_t)mb * DD + col;   // +r*DD, +t*BD

  // prefetch A, z for t = 0
  float pa[4], pz[4];
#pragma unroll
  for (int r = 0; r < 4; ++r) {
    pa[r] = outs[gbase + (size_t)r * DD];
    pz[r] = z[gbase + (size_t)r * DD];
  }

  for (int t = 0; t < TT; ++t) {
    const short* __restrict__ Hg = (t & 1) ? hb1 : hb0;
    short* __restrict__ Hn = (t & 1) ? hb0 : hb1;
    const short* hrow = Hg + (size_t)mrow * DD + hi8;

    f32x4 v0 = (f32x4){0,0,0,0}, v1 = (f32x4){0,0,0,0};
    f32x4 v2 = (f32x4){0,0,0,0}, v3 = (f32x4){0,0,0,0};
#pragma unroll 4
    for (int c = 0; c < 48; c += 4) {
      short8 aa0 = *(const short8*)(hrow + (c + 0) * 32);
      short8 bb0 = *(const short8*)&WhS[(bRow + (c + 0) * 32 + hi8) ^ bSwz];
      v0 = __builtin_amdgcn_mfma_f32_16x16x32_bf16(aa0, bb0, v0, 0, 0, 0);
      short8 aa1 = *(const short8*)(hrow + (c + 1) * 32);
      short8 bb1 = *(const short8*)&WhS[(bRow + (c + 1) * 32 + hi8) ^ bSwz];
      v1 = __builtin_amdgcn_mfma_f32_16x16x32_bf16(aa1, bb1, v1, 0, 0, 0);
      short8 aa2 = *(const short8*)(hrow + (c + 2) * 32);
      short8 bb2 = *(const short8*)&WhS[(bRow + (c + 2) * 32 + hi8) ^ bSwz];
      v2 = __builtin_amdgcn_mfma_f32_16x16x32_bf16(aa2, bb2, v2, 0, 0, 0);
      short8 aa3 = *(const short8*)(hrow + (c + 3) * 32);
      short8 bb3 = *(const short8*)&WhS[(bRow + (c + 3) * 32 + hi8) ^ bSwz];
      v3 = __builtin_amdgcn_mfma_f32_16x16x32_bf16(aa3, bb3, v3, 0, 0, 0);
    }
    f32x4 accS = (v0 + v1) + (v2 + v3);

    // critical-path epilogue: h_new + Hn store only
    float hv[4];
#pragma unroll
    for (int r = 0; r < 4; ++r) {
      float pre = pa[r] + sv * accS[r];
      hv[r] = tanhf(pre);
      Hn[(size_t)(mb + r) * DD + col] = f2bf(hv[r]);
    }

    const bool last = (t == TT - 1);
    if (!last) {
      __threadfence();          // release: drain Hn to coherence point
      __syncthreads();          // all threads' fences done
      if (tid == 0) atomicAdd(bar, 1);
    }

    // off-critical-path: hall / outs stores (overlap the spin)
    size_t tb = (size_t)t * BD;
#pragma unroll
    for (int r = 0; r < 4; ++r) {
      size_t gi = tb + gbase + (size_t)r * DD;
      hall[gi + BD] = hv[r];
      float zz = pz[r];
      outs[gi] = hv[r] * (zz / (1.f + __expf(-zz)));
    }
    // prefetch A, z for t+1 (overlap the spin)
    if (!last) {
      size_t nb = tb + BD + gbase;
#pragma unroll
      for (int r = 0; r < 4; ++r) {
        pa[r] = outs[nb + (size_t)r * DD];
        pz[r] = z[nb + (size_t)r * DD];
      }
      if (tid == 0) {
        int target = NWG * (t + 2);
        while (__hip_atomic_load(bar, __ATOMIC_RELAXED, __HIP_MEMORY_SCOPE_AGENT) < target)
          __builtin_amdgcn_s_sleep(2);
      }
      __syncthreads();
      __threadfence();          // acquire: invalidate stale h lines (L1+L2)
    }
  }
}

// ---------------- launcher ----------------
extern "C" void kernel_launch(void* const* d_in, const int* in_sizes, int n_in,
                              void* d_out, int out_size, void* d_ws, size_t ws_size,
                              hipStream_t stream) {
  const float* x  = (const float*)d_in[0];
  const float* z  = (const float*)d_in[1];
  const float* h0 = (const float*)d_in[2];
  const float* Wx = (const float*)d_in[3];
  const float* Wh = (const float*)d_in[4];
  const float* b  = (const float*)d_in[5];
  const float* lr = (const float*)d_in[6];
  const float* u  = (const float*)d_in[7];

  float* outs = (float*)d_out;
  float* hall = outs + (size_t)TBD;

  char* ws = (char*)d_ws;
  float* vA = (float*)ws;
  float* vB = vA + DD;
  float* vC = vB + DD;
  float* vD = vC + DD;
  float* sS = vD + DD;
  int*   bar = (int*)(ws + 16384);        // own cacheline region
  short* hb0 = (short*)(ws + 32768);
  short* hb1 = hb0 + BD;

  // phase 1: big GEMM (independent; enqueue first)
  hipLaunchKernelGGL(k_gemm_xA, dim3(12, 256), dim3(256), 0, stream, x, Wx, b, outs);

  // phase 0: power iteration
  hipMemsetAsync(vA, 0, DD * sizeof(float), stream);
  hipLaunchKernelGGL(k_matvec_col, dim3(6, 8), dim3(256), 0, stream, Wh, u, vA);
  hipLaunchKernelGGL(k_matvec_row, dim3(384), dim3(256), 0, stream, Wh, vA, vB);
  hipMemsetAsync(vA, 0, DD * sizeof(float), stream);
  hipLaunchKernelGGL(k_matvec_col, dim3(6, 8), dim3(256), 0, stream, Wh, vB, vA);
  hipLaunchKernelGGL(k_matvec_row, dim3(384), dim3(256), 0, stream, Wh, vA, vB);
  hipMemsetAsync(vC, 0, DD * sizeof(float), stream);
  hipLaunchKernelGGL(k_matvec_col, dim3(6, 8), dim3(256), 0, stream, Wh, vB, vC);
  hipLaunchKernelGGL(k_matvec_row, dim3(384), dim3(256), 0, stream, Wh, vC, vD);
  hipLaunchKernelGGL(k_scale, dim3(1), dim3(256), 0, stream, vC, vD, lr, sS);

  // zero barrier counter (graph-capture-safe, per-launch)
  hipMemsetAsync(bar, 0, sizeof(int), stream);

  // phase 2: cooperative launch guarantees co-residency (custom barrier inside)
  void* args[9] = {(void*)&Wh, (void*)&h0, (void*)&z, (void*)&sS,
                   (void*)&outs, (void*)&hall, (void*)&hb0, (void*)&hb1, (void*)&bar};
  hipLaunchCooperativeKernel((const void*)k_recur, dim3(NWG), dim3(256), args, 0, stream);
}

// Round 3
// 7384.903 us; speedup vs baseline: 2.3465x; 1.8113x over previous
//
#include <hip/hip_runtime.h>

#define DD 1536
#define TT 512
#define BB 64
#define BD (BB*DD)      /* 98304 */
#define TBD (TT*BD)     /* 50331648 */
#define NWG 96

typedef __attribute__((ext_vector_type(8))) short short8;
typedef __attribute__((ext_vector_type(4))) short short4v;
typedef __attribute__((ext_vector_type(4))) float f32x4;
typedef unsigned long long u64;
typedef __attribute__((ext_vector_type(2))) unsigned long long u64x2;

__device__ __forceinline__ short f2bf(float f) {
  unsigned u = __builtin_bit_cast(unsigned, f);
  u += 0x7FFFu + ((u >> 16) & 1u);   // RNE
  return (short)(u >> 16);
}

// coherent (device-scope, L1/L2-bypassing) 2-byte store: data goes to the
// coherence point (Infinity Cache) -> no L2 dirty state, no fences needed.
__device__ __forceinline__ void st_coh_b16(short* p, unsigned v) {
  asm volatile("global_store_short %0, %1, off sc0 sc1" :: "v"(p), "v"(v) : "memory");
}

// ---------------- power iteration helpers (f32 exact) ----------------

__global__ __launch_bounds__(256) void k_matvec_row(
    const float* __restrict__ W, const float* __restrict__ x, float* __restrict__ y) {
  int wave = (blockIdx.x * 256 + threadIdx.x) >> 6;
  int lane = threadIdx.x & 63;
  const float* Wr = W + (size_t)wave * DD;
  float acc = 0.f;
  for (int j = lane; j < DD; j += 64) acc += Wr[j] * x[j];
  for (int off = 32; off; off >>= 1) acc += __shfl_down(acc, off, 64);
  if (lane == 0) y[wave] = acc;
}

__global__ __launch_bounds__(256) void k_matvec_col(
    const float* __restrict__ W, const float* __restrict__ x, float* __restrict__ y) {
  int j = blockIdx.x * 256 + threadIdx.x;
  int i0 = blockIdx.y * 192;
  float acc = 0.f;
  for (int i = i0; i < i0 + 192; ++i) acc += W[(size_t)i * DD + j] * x[i];
  atomicAdd(&y[j], acc);
}

__global__ __launch_bounds__(256) void k_scale(
    const float* __restrict__ t5, const float* __restrict__ t6,
    const float* __restrict__ log_radius, float* __restrict__ s_out) {
  __shared__ float red[8];
  int tid = threadIdx.x;
  float a5 = 0.f, a6 = 0.f;
  for (int i = tid; i < DD; i += 256) { float v5 = t5[i], v6 = t6[i]; a5 += v5*v5; a6 += v6*v6; }
  for (int off = 32; off; off >>= 1) { a5 += __shfl_down(a5, off, 64); a6 += __shfl_down(a6, off, 64); }
  int w = tid >> 6, lane = tid & 63;
  if (lane == 0) { red[w] = a5; red[4 + w] = a6; }
  __syncthreads();
  if (tid == 0) {
    float s5 = red[0] + red[1] + red[2] + red[3];
    float s6 = red[4] + red[5] + red[6] + red[7];
    float sigma = sqrtf(s6 / s5);
    float lr = log_radius[0];
    float target = 0.999f / (1.f + expf(-lr));
    s_out[0] = target / (sigma + 1e-8f);
  }
}

// ---------------- phase 1: A = x @ Wx^T + b -> d_out[outs region] ----------------
__global__ __launch_bounds__(256) void k_gemm_xA(
    const float* __restrict__ x, const float* __restrict__ Wx,
    const float* __restrict__ bias, float* __restrict__ Aout) {
  __shared__ short As[128 * 64];
  __shared__ short Bs[128 * 64];
  const int tid = threadIdx.x;
  const int lane = tid & 63;
  const int w = tid >> 6;
  const int n0 = blockIdx.x * 128;
  const int m0 = blockIdx.y * 128;
  const int mq = (w >> 1) * 64;
  const int nq = (w & 1) * 64;

  f32x4 acc[4][4];
#pragma unroll
  for (int i = 0; i < 4; ++i)
#pragma unroll
    for (int j = 0; j < 4; ++j) acc[i][j] = (f32x4){0.f, 0.f, 0.f, 0.f};

  const int r0 = tid >> 3;
  const int c8 = tid & 7;

  for (int k0 = 0; k0 < DD; k0 += 64) {
    __syncthreads();
#pragma unroll
    for (int c = 0; c < 4; ++c) {
      int row = c * 32 + r0;
      const float4* gx = (const float4*)(x + (size_t)(m0 + row) * DD + k0 + c8 * 8);
      const float4* gw = (const float4*)(Wx + (size_t)(n0 + row) * DD + k0 + c8 * 8);
      float4 x0 = gx[0], x1 = gx[1];
      float4 w0 = gw[0], w1 = gw[1];
      short8 xv, wv;
      xv[0]=f2bf(x0.x); xv[1]=f2bf(x0.y); xv[2]=f2bf(x0.z); xv[3]=f2bf(x0.w);
      xv[4]=f2bf(x1.x); xv[5]=f2bf(x1.y); xv[6]=f2bf(x1.z); xv[7]=f2bf(x1.w);
      wv[0]=f2bf(w0.x); wv[1]=f2bf(w0.y); wv[2]=f2bf(w0.z); wv[3]=f2bf(w0.w);
      wv[4]=f2bf(w1.x); wv[5]=f2bf(w1.y); wv[6]=f2bf(w1.z); wv[7]=f2bf(w1.w);
      int so = (row * 64 + c8 * 8) ^ ((row & 7) << 3);
      *(short8*)&As[so] = xv;
      *(short8*)&Bs[so] = wv;
    }
    __syncthreads();
#pragma unroll
    for (int kk = 0; kk < 64; kk += 32) {
      short8 af[4], bfr[4];
#pragma unroll
      for (int f = 0; f < 4; ++f) {
        int ar = mq + f * 16 + (lane & 15);
        int k = kk + ((lane >> 4) << 3);
        af[f] = *(const short8*)&As[(ar * 64 + k) ^ ((ar & 7) << 3)];
        int br = nq + f * 16 + (lane & 15);
        bfr[f] = *(const short8*)&Bs[(br * 64 + k) ^ ((br & 7) << 3)];
      }
#pragma unroll
      for (int i = 0; i < 4; ++i)
#pragma unroll
        for (int j = 0; j < 4; ++j)
          acc[i][j] = __builtin_amdgcn_mfma_f32_16x16x32_bf16(af[i], bfr[j], acc[i][j], 0, 0, 0);
    }
  }
#pragma unroll
  for (int i = 0; i < 4; ++i) {
    int rbase = m0 + mq + i * 16 + ((lane >> 4) << 2);
#pragma unroll
    for (int j = 0; j < 4; ++j) {
      int col = n0 + nq + j * 16 + (lane & 15);
      float bv = bias[col];
#pragma unroll
      for (int r = 0; r < 4; ++r)
        Aout[(size_t)(rbase + r) * DD + col] = acc[i][j][r] + bv;
    }
  }
}

// ---------------- phase 2: sequential recurrence, fence-free coherent protocol ----------------
// h ping-pong buffers are ONLY ever touched with coherent (sc0 sc1) ops:
//   writes:  global_store_short sc0 sc1  (write-through to Infinity Cache)
//   reads:   __hip_atomic_load relaxed/agent (8B, bypasses L1/L2, compiler-tracked)
// Barrier: s_waitcnt vmcnt(0) (stores acked at IF) -> __syncthreads -> relaxed
// fetch_add arrival; readers spin on the counter at IF. No __threadfence (no
// buffer_wbl2 / buffer_inv) in the steady-state loop.
__global__ __launch_bounds__(256) void k_recur(
    const float* __restrict__ Wh, const float* __restrict__ h0,
    const float* __restrict__ z, const float* __restrict__ sp,
    float* __restrict__ outs, float* __restrict__ hall,
    short* __restrict__ hb0, short* __restrict__ hb1, int* __restrict__ bar) {
  __shared__ short WhS[16 * DD];   // 48 KB
  const int tid = threadIdx.x;
  const int lane = tid & 63;
  const int w = tid >> 6;
  const int n0 = blockIdx.x * 16;

  // load Wh slice -> LDS bf16, swizzled
#pragma unroll
  for (int c = 0; c < 12; ++c) {
    int idx = c * 256 + tid;
    int row = idx / 192;
    int cc = idx - row * 192;
    const float4* g = (const float4*)(Wh + (size_t)(n0 + row) * DD + cc * 8);
    float4 a0 = g[0], a1 = g[1];
    short8 v;
    v[0]=f2bf(a0.x); v[1]=f2bf(a0.y); v[2]=f2bf(a0.z); v[3]=f2bf(a0.w);
    v[4]=f2bf(a1.x); v[5]=f2bf(a1.y); v[6]=f2bf(a1.z); v[7]=f2bf(a1.w);
    int so = (row * DD + cc * 8) ^ ((row & 7) << 3);
    *(short8*)&WhS[so] = v;
  }
  // init: h_all[0] = h0 (f32, plain); hb0 = bf16(h0) via coherent 8B stores
  {
    int base = (blockIdx.x * 256 + tid) * 4;
    float4 v = *(const float4*)(h0 + base);
    *(float4*)(hall + base) = v;
    u64 pk = (u64)(unsigned short)f2bf(v.x)
           | ((u64)(unsigned short)f2bf(v.y) << 16)
           | ((u64)(unsigned short)f2bf(v.z) << 32)
           | ((u64)(unsigned short)f2bf(v.w) << 48);
    __hip_atomic_store((u64*)(hb0 + base), pk, __ATOMIC_RELAXED, __HIP_MEMORY_SCOPE_AGENT);
  }
  const float sv = sp[0];

  // ---- initial barrier ----
  asm volatile("s_waitcnt vmcnt(0)" ::: "memory");
  __syncthreads();
  if (tid == 0) {
    __hip_atomic_fetch_add(bar, 1, __ATOMIC_RELAXED, __HIP_MEMORY_SCOPE_AGENT);
    while (__hip_atomic_load(bar, __ATOMIC_RELAXED, __HIP_MEMORY_SCOPE_AGENT) < NWG)
      __builtin_amdgcn_s_sleep(1);
  }
  __syncthreads();

  const int nl = lane & 15;
  const int hi8 = (lane >> 4) << 3;
  const int bRow = nl * DD;
  const int bSwz = (nl & 7) << 3;
  const int mrow = w * 16 + nl;
  const int col = n0 + nl;
  const int mb = w * 16 + ((lane >> 4) << 2);
  const size_t gbase = (size_t)mb * DD + col;   // +r*DD, +t*BD
  const int qo = hi8 >> 2;                      // u64 offset within 32-short chunk

  // prefetch A, z for t = 0 (plain cached loads)
  float pa[4], pz[4];
#pragma unroll
  for (int r = 0; r < 4; ++r) {
    pa[r] = outs[gbase + (size_t)r * DD];
    pz[r] = z[gbase + (size_t)r * DD];
  }

  for (int t = 0; t < TT; ++t) {
    const short* Hg = (t & 1) ? hb1 : hb0;
    short* Hn = (t & 1) ? hb0 : hb1;
    const u64* hq = (const u64*)(Hg + (size_t)mrow * DD) + qo;

    f32x4 v0 = (f32x4){0,0,0,0}, v1 = (f32x4){0,0,0,0};
    f32x4 v2 = (f32x4){0,0,0,0}, v3 = (f32x4){0,0,0,0};
#pragma unroll 4
    for (int c = 0; c < 48; c += 4) {
      u64x2 q0, q1, q2, q3;
      q0[0] = __hip_atomic_load(hq + (c+0)*8,     __ATOMIC_RELAXED, __HIP_MEMORY_SCOPE_AGENT);
      q0[1] = __hip_atomic_load(hq + (c+0)*8 + 1, __ATOMIC_RELAXED, __HIP_MEMORY_SCOPE_AGENT);
      short8 bb0 = *(const short8*)&WhS[(bRow + (c + 0) * 32 + hi8) ^ bSwz];
      v0 = __builtin_amdgcn_mfma_f32_16x16x32_bf16(__builtin_bit_cast(short8, q0), bb0, v0, 0, 0, 0);
      q1[0] = __hip_atomic_load(hq + (c+1)*8,     __ATOMIC_RELAXED, __HIP_MEMORY_SCOPE_AGENT);
      q1[1] = __hip_atomic_load(hq + (c+1)*8 + 1, __ATOMIC_RELAXED, __HIP_MEMORY_SCOPE_AGENT);
      short8 bb1 = *(const short8*)&WhS[(bRow + (c + 1) * 32 + hi8) ^ bSwz];
      v1 = __builtin_amdgcn_mfma_f32_16x16x32_bf16(__builtin_bit_cast(short8, q1), bb1, v1, 0, 0, 0);
      q2[0] = __hip_atomic_load(hq + (c+2)*8,     __ATOMIC_RELAXED, __HIP_MEMORY_SCOPE_AGENT);
      q2[1] = __hip_atomic_load(hq + (c+2)*8 + 1, __ATOMIC_RELAXED, __HIP_MEMORY_SCOPE_AGENT);
      short8 bb2 = *(const short8*)&WhS[(bRow + (c + 2) * 32 + hi8) ^ bSwz];
      v2 = __builtin_amdgcn_mfma_f32_16x16x32_bf16(__builtin_bit_cast(short8, q2), bb2, v2, 0, 0, 0);
      q3[0] = __hip_atomic_load(hq + (c+3)*8,     __ATOMIC_RELAXED, __HIP_MEMORY_SCOPE_AGENT);
      q3[1] = __hip_atomic_load(hq + (c+3)*8 + 1, __ATOMIC_RELAXED, __HIP_MEMORY_SCOPE_AGENT);
      short8 bb3 = *(const short8*)&WhS[(bRow + (c + 3) * 32 + hi8) ^ bSwz];
      v3 = __builtin_amdgcn_mfma_f32_16x16x32_bf16(__builtin_bit_cast(short8, q3), bb3, v3, 0, 0, 0);
    }
    f32x4 accS = (v0 + v1) + (v2 + v3);

    // critical-path epilogue: h_new + coherent Hn stores only (math identical to R2)
    float hv[4];
#pragma unroll
    for (int r = 0; r < 4; ++r) {
      float pre = pa[r] + sv * accS[r];
      hv[r] = tanhf(pre);
    }
#pragma unroll
    for (int r = 0; r < 4; ++r)
      st_coh_b16(Hn + (size_t)(mb + r) * DD + col, (unsigned)(unsigned short)f2bf(hv[r]));

    const bool last = (t == TT - 1);
    if (!last) {
      asm volatile("s_waitcnt vmcnt(0)" ::: "memory");  // Hn stores acked at IF (all waves)
      __syncthreads();
      if (tid == 0)
        __hip_atomic_fetch_add(bar, 1, __ATOMIC_RELAXED, __HIP_MEMORY_SCOPE_AGENT);
    }

    // off-critical-path: hall / outs stores (plain cached), overlap the spin
    size_t tb = (size_t)t * BD;
#pragma unroll
    for (int r = 0; r < 4; ++r) {
      size_t gi = tb + gbase + (size_t)r * DD;
      hall[gi + BD] = hv[r];
      float zz = pz[r];
      outs[gi] = hv[r] * (zz / (1.f + __expf(-zz)));
    }
    // prefetch A, z for t+1 (overlap the spin)
    if (!last) {
      size_t nb = tb + BD + gbase;
#pragma unroll
      for (int r = 0; r < 4; ++r) {
        pa[r] = outs[nb + (size_t)r * DD];
        pz[r] = z[nb + (size_t)r * DD];
      }
      if (tid == 0) {
        int target = NWG * (t + 2);
        while (__hip_atomic_load(bar, __ATOMIC_RELAXED, __HIP_MEMORY_SCOPE_AGENT) < target)
          __builtin_amdgcn_s_sleep(1);
      }
      __syncthreads();   // releases all waves; subsequent coherent loads fetch from IF
    }
  }
}

// ---------------- launcher ----------------
extern "C" void kernel_launch(void* const* d_in, const int* in_sizes, int n_in,
                              void* d_out, int out_size, void* d_ws, size_t ws_size,
                              hipStream_t stream) {
  const float* x  = (const float*)d_in[0];
  const float* z  = (const float*)d_in[1];
  const float* h0 = (const float*)d_in[2];
  const float* Wx = (const float*)d_in[3];
  const float* Wh = (const float*)d_in[4];
  const float* b  = (const float*)d_in[5];
  const float* lr = (const float*)d_in[6];
  const float* u  = (const float*)d_in[7];

  float* outs = (float*)d_out;
  float* hall = outs + (size_t)TBD;

  char* ws = (char*)d_ws;
  float* vA = (float*)ws;
  float* vB = vA + DD;
  float* vC = vB + DD;
  float* vD = vC + DD;
  float* sS = vD + DD;
  int*   bar = (int*)(ws + 16384);
  short* hb0 = (short*)(ws + 32768);
  short* hb1 = hb0 + BD;

  // phase 1: big GEMM (independent; enqueue first)
  hipLaunchKernelGGL(k_gemm_xA, dim3(12, 256), dim3(256), 0, stream, x, Wx, b, outs);

  // phase 0: power iteration
  hipMemsetAsync(vA, 0, DD * sizeof(float), stream);
  hipLaunchKernelGGL(k_matvec_col, dim3(6, 8), dim3(256), 0, stream, Wh, u, vA);
  hipLaunchKernelGGL(k_matvec_row, dim3(384), dim3(256), 0, stream, Wh, vA, vB);
  hipMemsetAsync(vA, 0, DD * sizeof(float), stream);
  hipLaunchKernelGGL(k_matvec_col, dim3(6, 8), dim3(256), 0, stream, Wh, vB, vA);
  hipLaunchKernelGGL(k_matvec_row, dim3(384), dim3(256), 0, stream, Wh, vA, vB);
  hipMemsetAsync(vC, 0, DD * sizeof(float), stream);
  hipLaunchKernelGGL(k_matvec_col, dim3(6, 8), dim3(256), 0, stream, Wh, vB, vC);
  hipLaunchKernelGGL(k_matvec_row, dim3(384), dim3(256), 0, stream, Wh, vC, vD);
  hipLaunchKernelGGL(k_scale, dim3(1), dim3(256), 0, stream, vC, vD, lr, sS);

  // zero barrier counter (graph-capture-safe, per-launch)
  hipMemsetAsync(bar, 0, sizeof(int), stream);

  // phase 2: cooperative launch guarantees co-residency (custom barrier inside)
  void* args[9] = {(void*)&Wh, (void*)&h0, (void*)&z, (void*)&sS,
                   (void*)&outs, (void*)&hall, (void*)&hb0, (void*)&hb1, (void*)&bar};
  hipLaunchCooperativeKernel((const void*)k_recur, dim3(NWG), dim3(256), args, 0, stream);
}

// Round 4
// 5796.724 us; speedup vs baseline: 2.9894x; 1.2740x over previous
//
#include <hip/hip_runtime.h>

#define DD 1536
#define TT 512
#define BB 64
#define BD (BB*DD)      /* 98304 */
#define TBD (TT*BD)     /* 50331648 */
#define NWG 384         /* 96 feature-blocks x 4 batch-quadrants */

typedef __attribute__((ext_vector_type(8))) short short8;
typedef __attribute__((ext_vector_type(4))) float f32x4;
typedef unsigned long long u64;

__device__ __forceinline__ short f2bf(float f) {
  unsigned u = __builtin_bit_cast(unsigned, f);
  u += 0x7FFFu + ((u >> 16) & 1u);   // RNE
  return (short)(u >> 16);
}

// coherent (device-scope, L1/L2-bypassing) 2-byte store -> Infinity Cache
__device__ __forceinline__ void st_coh_b16(short* p, unsigned v) {
  asm volatile("global_store_short %0, %1, off sc0 sc1" :: "v"(p), "v"(v) : "memory");
}

// coherent 16B load from Infinity Cache (bypasses L1/L2)
#define LD_COH_B128(dst, addr, imm) \
  asm volatile("global_load_dwordx4 %0, %1, off offset:" #imm " sc0 sc1" \
               : "=v"(dst) : "v"(addr) : "memory")

// ---------------- power iteration helpers (f32 exact) ----------------

__global__ __launch_bounds__(256) void k_matvec_row(
    const float* __restrict__ W, const float* __restrict__ x, float* __restrict__ y) {
  int wave = (blockIdx.x * 256 + threadIdx.x) >> 6;
  int lane = threadIdx.x & 63;
  const float* Wr = W + (size_t)wave * DD;
  float acc = 0.f;
  for (int j = lane; j < DD; j += 64) acc += Wr[j] * x[j];
  for (int off = 32; off; off >>= 1) acc += __shfl_down(acc, off, 64);
  if (lane == 0) y[wave] = acc;
}

__global__ __launch_bounds__(256) void k_matvec_col(
    const float* __restrict__ W, const float* __restrict__ x, float* __restrict__ y) {
  int j = blockIdx.x * 256 + threadIdx.x;
  int i0 = blockIdx.y * 192;
  float acc = 0.f;
  for (int i = i0; i < i0 + 192; ++i) acc += W[(size_t)i * DD + j] * x[i];
  atomicAdd(&y[j], acc);
}

__global__ __launch_bounds__(256) void k_scale(
    const float* __restrict__ t5, const float* __restrict__ t6,
    const float* __restrict__ log_radius, float* __restrict__ s_out) {
  __shared__ float red[8];
  int tid = threadIdx.x;
  float a5 = 0.f, a6 = 0.f;
  for (int i = tid; i < DD; i += 256) { float v5 = t5[i], v6 = t6[i]; a5 += v5*v5; a6 += v6*v6; }
  for (int off = 32; off; off >>= 1) { a5 += __shfl_down(a5, off, 64); a6 += __shfl_down(a6, off, 64); }
  int w = tid >> 6, lane = tid & 63;
  if (lane == 0) { red[w] = a5; red[4 + w] = a6; }
  __syncthreads();
  if (tid == 0) {
    float s5 = red[0] + red[1] + red[2] + red[3];
    float s6 = red[4] + red[5] + red[6] + red[7];
    float sigma = sqrtf(s6 / s5);
    float lr = log_radius[0];
    float target = 0.999f / (1.f + expf(-lr));
    s_out[0] = target / (sigma + 1e-8f);
  }
}

// ---------------- phase 1: A = x @ Wx^T + b -> d_out[outs region] ----------------
__global__ __launch_bounds__(256) void k_gemm_xA(
    const float* __restrict__ x, const float* __restrict__ Wx,
    const float* __restrict__ bias, float* __restrict__ Aout) {
  __shared__ short As[128 * 64];
  __shared__ short Bs[128 * 64];
  const int tid = threadIdx.x;
  const int lane = tid & 63;
  const int w = tid >> 6;
  const int n0 = blockIdx.x * 128;
  const int m0 = blockIdx.y * 128;
  const int mq = (w >> 1) * 64;
  const int nq = (w & 1) * 64;

  f32x4 acc[4][4];
#pragma unroll
  for (int i = 0; i < 4; ++i)
#pragma unroll
    for (int j = 0; j < 4; ++j) acc[i][j] = (f32x4){0.f, 0.f, 0.f, 0.f};

  const int r0 = tid >> 3;
  const int c8 = tid & 7;

  for (int k0 = 0; k0 < DD; k0 += 64) {
    __syncthreads();
#pragma unroll
    for (int c = 0; c < 4; ++c) {
      int row = c * 32 + r0;
      const float4* gx = (const float4*)(x + (size_t)(m0 + row) * DD + k0 + c8 * 8);
      const float4* gw = (const float4*)(Wx + (size_t)(n0 + row) * DD + k0 + c8 * 8);
      float4 x0 = gx[0], x1 = gx[1];
      float4 w0 = gw[0], w1 = gw[1];
      short8 xv, wv;
      xv[0]=f2bf(x0.x); xv[1]=f2bf(x0.y); xv[2]=f2bf(x0.z); xv[3]=f2bf(x0.w);
      xv[4]=f2bf(x1.x); xv[5]=f2bf(x1.y); xv[6]=f2bf(x1.z); xv[7]=f2bf(x1.w);
      wv[0]=f2bf(w0.x); wv[1]=f2bf(w0.y); wv[2]=f2bf(w0.z); wv[3]=f2bf(w0.w);
      wv[4]=f2bf(w1.x); wv[5]=f2bf(w1.y); wv[6]=f2bf(w1.z); wv[7]=f2bf(w1.w);
      int so = (row * 64 + c8 * 8) ^ ((row & 7) << 3);
      *(short8*)&As[so] = xv;
      *(short8*)&Bs[so] = wv;
    }
    __syncthreads();
#pragma unroll
    for (int kk = 0; kk < 64; kk += 32) {
      short8 af[4], bfr[4];
#pragma unroll
      for (int f = 0; f < 4; ++f) {
        int ar = mq + f * 16 + (lane & 15);
        int k = kk + ((lane >> 4) << 3);
        af[f] = *(const short8*)&As[(ar * 64 + k) ^ ((ar & 7) << 3)];
        int br = nq + f * 16 + (lane & 15);
        bfr[f] = *(const short8*)&Bs[(br * 64 + k) ^ ((br & 7) << 3)];
      }
#pragma unroll
      for (int i = 0; i < 4; ++i)
#pragma unroll
        for (int j = 0; j < 4; ++j)
          acc[i][j] = __builtin_amdgcn_mfma_f32_16x16x32_bf16(af[i], bfr[j], acc[i][j], 0, 0, 0);
    }
  }
#pragma unroll
  for (int i = 0; i < 4; ++i) {
    int rbase = m0 + mq + i * 16 + ((lane >> 4) << 2);
#pragma unroll
    for (int j = 0; j < 4; ++j) {
      int col = n0 + nq + j * 16 + (lane & 15);
      float bv = bias[col];
#pragma unroll
      for (int r = 0; r < 4; ++r)
        Aout[(size_t)(rbase + r) * DD + col] = acc[i][j][r] + bv;
    }
  }
}

// ---------------- phase 2: recurrence, 384 WGs, 16x16 tile per WG ----------------
// WG (nb, mq): rows 16*mq..+15, features 16*nb..+15, full K=1536.
// 4 waves K-split (384 each, 12 MFMA), LDS cross-wave reduce, 1 elem/thread epilogue.
// h exchange: coherent stores (sc0 sc1) / coherent dwordx4 loads; fence-free.
// Barrier: 4 padded counters (96 arrivals each), threads 0..3 poll.
__global__ __launch_bounds__(256) void k_recur(
    const float* __restrict__ Wh, const float* __restrict__ h0,
    const float* __restrict__ z, const float* __restrict__ sp,
    float* __restrict__ outs, float* __restrict__ hall,
    short* __restrict__ hb0, short* __restrict__ hb1, int* __restrict__ bars) {
  __shared__ short WhS[16 * DD];   // 48 KB
  __shared__ f32x4 REDS[4 * 64];   // 4 KB
  const int tid = threadIdx.x;
  const int lane = tid & 63;
  const int wv = tid >> 6;
  const int wgid = blockIdx.x;
  const int nb = wgid >> 2;
  const int mq = wgid & 3;
  const int n0 = nb * 16;
  const int m0 = mq * 16;

  // stage Wh rows n0..n0+15 -> LDS bf16, XOR-swizzled
#pragma unroll
  for (int c = 0; c < 12; ++c) {
    int idx = c * 256 + tid;          // 0..3071
    int row = idx / 192;
    int cc = idx - row * 192;
    const float4* g = (const float4*)(Wh + (size_t)(n0 + row) * DD + cc * 8);
    float4 a0 = g[0], a1 = g[1];
    short8 v;
    v[0]=f2bf(a0.x); v[1]=f2bf(a0.y); v[2]=f2bf(a0.z); v[3]=f2bf(a0.w);
    v[4]=f2bf(a1.x); v[5]=f2bf(a1.y); v[6]=f2bf(a1.z); v[7]=f2bf(a1.w);
    int so = (row * DD + cc * 8) ^ ((row & 7) << 3);
    *(short8*)&WhS[so] = v;
  }
  // init (first 96 WGs): hall[0] = h0 (f32), hb0 = bf16(h0) coherent
  if (wgid < 96) {
    int base = (wgid * 256 + tid) * 4;
    float4 v = *(const float4*)(h0 + base);
    *(float4*)(hall + base) = v;
    u64 pk = (u64)(unsigned short)f2bf(v.x)
           | ((u64)(unsigned short)f2bf(v.y) << 16)
           | ((u64)(unsigned short)f2bf(v.z) << 32)
           | ((u64)(unsigned short)f2bf(v.w) << 48);
    __hip_atomic_store((u64*)(hb0 + base), pk, __ATOMIC_RELAXED, __HIP_MEMORY_SCOPE_AGENT);
  }
  const float sv = sp[0];

  // ---- initial barrier (target 96*1 per counter) ----
  asm volatile("s_waitcnt vmcnt(0)" ::: "memory");
  __syncthreads();
  if (tid == 0)
    __hip_atomic_fetch_add(&bars[(wgid & 3) * 64], 1, __ATOMIC_RELAXED, __HIP_MEMORY_SCOPE_AGENT);
  if (tid < 4) {
    while (__hip_atomic_load(&bars[tid * 64], __ATOMIC_RELAXED, __HIP_MEMORY_SCOPE_AGENT) < 96)
      __builtin_amdgcn_s_sleep(1);
  }
  __syncthreads();

  // per-thread geometry
  const int arow = lane & 15;              // A row within tile / B feature col
  const int hi8 = (lane >> 4) << 3;        // k-octet within 32-wide k-step
  const int kw = wv * 384;                 // wave's K-slice base
  const int bbase = arow * DD;             // B (WhS) row base, shorts
  const int bSwz = (lane & 7) << 3;        // swizzle for B reads
  const int r = tid >> 4;                  // epilogue: output row 0..15
  const int c = tid & 15;                  // epilogue: output col 0..15
  const int l2 = ((r >> 2) << 4) | c;      // lane holding (r,c) partial
  const int ri = r & 3;                    // reg index within f32x4
  const int grow = m0 + r;                 // global batch row
  const int gcol = n0 + c;                 // global feature col
  const size_t eidx = (size_t)grow * DD + gcol;   // element offset in [B,D]
  const size_t aoff = (size_t)(m0 + arow) * DD + kw + hi8;  // A-load base, shorts

  // prefetch A, z for t = 0 (plain cached)
  float pa = outs[eidx];
  float pz = z[eidx];

  for (int t = 0; t < TT; ++t) {
    const short* Hg = (t & 1) ? hb1 : hb0;
    short* Hn = (t & 1) ? hb0 : hb1;
    const short* hp = Hg + aoff;

    // burst 12 coherent 16B A-loads (whole wave K-slice)
    short8 a0,a1,a2,a3,a4,a5,a6,a7,a8,a9,a10,a11;
    LD_COH_B128(a0,  hp, 0);
    LD_COH_B128(a1,  hp, 64);
    LD_COH_B128(a2,  hp, 128);
    LD_COH_B128(a3,  hp, 192);
    LD_COH_B128(a4,  hp, 256);
    LD_COH_B128(a5,  hp, 320);
    LD_COH_B128(a6,  hp, 384);
    LD_COH_B128(a7,  hp, 448);
    LD_COH_B128(a8,  hp, 512);
    LD_COH_B128(a9,  hp, 576);
    LD_COH_B128(a10, hp, 640);
    LD_COH_B128(a11, hp, 704);
    asm volatile("s_waitcnt vmcnt(0)" ::: "memory");
    __builtin_amdgcn_sched_barrier(0);

    f32x4 acc0 = (f32x4){0,0,0,0}, acc1 = (f32x4){0,0,0,0};
#define BFR(j) (*(const short8*)&WhS[(bbase + kw + (j)*32 + hi8) ^ bSwz])
    acc0 = __builtin_amdgcn_mfma_f32_16x16x32_bf16(a0,  BFR(0),  acc0, 0, 0, 0);
    acc1 = __builtin_amdgcn_mfma_f32_16x16x32_bf16(a1,  BFR(1),  acc1, 0, 0, 0);
    acc0 = __builtin_amdgcn_mfma_f32_16x16x32_bf16(a2,  BFR(2),  acc0, 0, 0, 0);
    acc1 = __builtin_amdgcn_mfma_f32_16x16x32_bf16(a3,  BFR(3),  acc1, 0, 0, 0);
    acc0 = __builtin_amdgcn_mfma_f32_16x16x32_bf16(a4,  BFR(4),  acc0, 0, 0, 0);
    acc1 = __builtin_amdgcn_mfma_f32_16x16x32_bf16(a5,  BFR(5),  acc1, 0, 0, 0);
    acc0 = __builtin_amdgcn_mfma_f32_16x16x32_bf16(a6,  BFR(6),  acc0, 0, 0, 0);
    acc1 = __builtin_amdgcn_mfma_f32_16x16x32_bf16(a7,  BFR(7),  acc1, 0, 0, 0);
    acc0 = __builtin_amdgcn_mfma_f32_16x16x32_bf16(a8,  BFR(8),  acc0, 0, 0, 0);
    acc1 = __builtin_amdgcn_mfma_f32_16x16x32_bf16(a9,  BFR(9),  acc1, 0, 0, 0);
    acc0 = __builtin_amdgcn_mfma_f32_16x16x32_bf16(a10, BFR(10), acc0, 0, 0, 0);
    acc1 = __builtin_amdgcn_mfma_f32_16x16x32_bf16(a11, BFR(11), acc1, 0, 0, 0);
#undef BFR

    // cross-wave K reduce via LDS
    REDS[wv * 64 + lane] = acc0 + acc1;
    __syncthreads();
    f32x4 p0 = REDS[l2], p1 = REDS[64 + l2], p2 = REDS[128 + l2], p3 = REDS[192 + l2];
    float ps = (p0[ri] + p1[ri]) + (p2[ri] + p3[ri]);

    // critical path: h_new + coherent store
    float hv = tanhf(pa + sv * ps);
    st_coh_b16(Hn + eidx, (unsigned)(unsigned short)f2bf(hv));

    const bool last = (t == TT - 1);
    if (!last) {
      asm volatile("s_waitcnt vmcnt(0)" ::: "memory");  // h store acked at IF
      __syncthreads();
      if (tid == 0)
        __hip_atomic_fetch_add(&bars[(wgid & 3) * 64], 1, __ATOMIC_RELAXED, __HIP_MEMORY_SCOPE_AGENT);
    }

    // off-critical-path tail (overlaps the spin)
    size_t tb = (size_t)t * BD;
    hall[tb + BD + eidx] = hv;
    float zz = pz;
    outs[tb + eidx] = hv * (zz / (1.f + __expf(-zz)));
    if (!last) {
      pa = outs[tb + BD + eidx];
      pz = z[tb + BD + eidx];
      if (tid < 4) {
        int target = 96 * (t + 2);
        while (__hip_atomic_load(&bars[tid * 64], __ATOMIC_RELAXED, __HIP_MEMORY_SCOPE_AGENT) < target)
          __builtin_amdgcn_s_sleep(1);
      }
      __syncthreads();
    }
  }
}

// ---------------- launcher ----------------
extern "C" void kernel_launch(void* const* d_in, const int* in_sizes, int n_in,
                              void* d_out, int out_size, void* d_ws, size_t ws_size,
                              hipStream_t stream) {
  const float* x  = (const float*)d_in[0];
  const float* z  = (const float*)d_in[1];
  const float* h0 = (const float*)d_in[2];
  const float* Wx = (const float*)d_in[3];
  const float* Wh = (const float*)d_in[4];
  const float* b  = (const float*)d_in[5];
  const float* lr = (const float*)d_in[6];
  const float* u  = (const float*)d_in[7];

  float* outs = (float*)d_out;
  float* hall = outs + (size_t)TBD;

  char* ws = (char*)d_ws;
  float* vA = (float*)ws;
  float* vB = vA + DD;
  float* vC = vB + DD;
  float* vD = vC + DD;
  float* sS = vD + DD;
  int*   bars = (int*)(ws + 16384);       // 4 counters, 256B apart
  short* hb0 = (short*)(ws + 32768);
  short* hb1 = hb0 + BD;

  // phase 1: big GEMM (independent; enqueue first)
  hipLaunchKernelGGL(k_gemm_xA, dim3(12, 256), dim3(256), 0, stream, x, Wx, b, outs);

  // phase 0: power iteration
  hipMemsetAsync(vA, 0, DD * sizeof(float), stream);
  hipLaunchKernelGGL(k_matvec_col, dim3(6, 8), dim3(256), 0, stream, Wh, u, vA);
  hipLaunchKernelGGL(k_matvec_row, dim3(384), dim3(256), 0, stream, Wh, vA, vB);
  hipMemsetAsync(vA, 0, DD * sizeof(float), stream);
  hipLaunchKernelGGL(k_matvec_col, dim3(6, 8), dim3(256), 0, stream, Wh, vB, vA);
  hipLaunchKernelGGL(k_matvec_row, dim3(384), dim3(256), 0, stream, Wh, vA, vB);
  hipMemsetAsync(vC, 0, DD * sizeof(float), stream);
  hipLaunchKernelGGL(k_matvec_col, dim3(6, 8), dim3(256), 0, stream, Wh, vB, vC);
  hipLaunchKernelGGL(k_matvec_row, dim3(384), dim3(256), 0, stream, Wh, vC, vD);
  hipLaunchKernelGGL(k_scale, dim3(1), dim3(256), 0, stream, vC, vD, lr, sS);

  // zero the 4 barrier counters (1 KB region)
  hipMemsetAsync(bars, 0, 1024, stream);

  // phase 2: cooperative launch (co-residency guaranteed; 52 KB LDS -> 3 WG/CU max)
  void* args[9] = {(void*)&Wh, (void*)&h0, (void*)&z, (void*)&sS,
                   (void*)&outs, (void*)&hall, (void*)&hb0, (void*)&hb1, (void*)&bars};
  hipLaunchCooperativeKernel((const void*)k_recur, dim3(NWG), dim3(256), args, 0, stream);
}

// Round 5
// 3889.845 us; speedup vs baseline: 4.4549x; 1.4902x over previous
//
#include <hip/hip_runtime.h>

#define DD 1536
#define TT 512
#define BB 64
#define BD (BB*DD)      /* 98304 */
#define TBD (TT*BD)     /* 50331648 */
#define NWG 384         /* 96 feature-blocks x 4 batch-quadrants */

typedef __attribute__((ext_vector_type(8))) short short8;
typedef __attribute__((ext_vector_type(4))) float f32x4;
typedef unsigned long long u64;

__device__ __forceinline__ short f2bf(float f) {
  unsigned u = __builtin_bit_cast(unsigned, f);
  u += 0x7FFFu + ((u >> 16) & 1u);   // RNE
  return (short)(u >> 16);
}

// coherent (device-scope, L1/L2-bypassing) stores -> Infinity Cache
__device__ __forceinline__ void st_coh_b16(short* p, unsigned v) {
  asm volatile("global_store_short %0, %1, off sc0 sc1" :: "v"(p), "v"(v) : "memory");
}
__device__ __forceinline__ void st_coh_b32(int* p, int v) {
  asm volatile("global_store_dword %0, %1, off sc0 sc1" :: "v"(p), "v"(v) : "memory");
}

// coherent 16B load from Infinity Cache (bypasses L1/L2)
#define LD_COH_B128(dst, addr, imm) \
  asm volatile("global_load_dwordx4 %0, %1, off offset:" #imm " sc0 sc1" \
               : "=v"(dst) : "v"(addr) : "memory")

// ---------------- power iteration helpers (f32 exact) ----------------

__global__ __launch_bounds__(256) void k_matvec_row(
    const float* __restrict__ W, const float* __restrict__ x, float* __restrict__ y) {
  int wave = (blockIdx.x * 256 + threadIdx.x) >> 6;
  int lane = threadIdx.x & 63;
  const float* Wr = W + (size_t)wave * DD;
  float acc = 0.f;
  for (int j = lane; j < DD; j += 64) acc += Wr[j] * x[j];
  for (int off = 32; off; off >>= 1) acc += __shfl_down(acc, off, 64);
  if (lane == 0) y[wave] = acc;
}

__global__ __launch_bounds__(256) void k_matvec_col(
    const float* __restrict__ W, const float* __restrict__ x, float* __restrict__ y) {
  int j = blockIdx.x * 256 + threadIdx.x;
  int i0 = blockIdx.y * 192;
  float acc = 0.f;
  for (int i = i0; i < i0 + 192; ++i) acc += W[(size_t)i * DD + j] * x[i];
  atomicAdd(&y[j], acc);
}

__global__ __launch_bounds__(256) void k_scale(
    const float* __restrict__ t5, const float* __restrict__ t6,
    const float* __restrict__ log_radius, float* __restrict__ s_out) {
  __shared__ float red[8];
  int tid = threadIdx.x;
  float a5 = 0.f, a6 = 0.f;
  for (int i = tid; i < DD; i += 256) { float v5 = t5[i], v6 = t6[i]; a5 += v5*v5; a6 += v6*v6; }
  for (int off = 32; off; off >>= 1) { a5 += __shfl_down(a5, off, 64); a6 += __shfl_down(a6, off, 64); }
  int w = tid >> 6, lane = tid & 63;
  if (lane == 0) { red[w] = a5; red[4 + w] = a6; }
  __syncthreads();
  if (tid == 0) {
    float s5 = red[0] + red[1] + red[2] + red[3];
    float s6 = red[4] + red[5] + red[6] + red[7];
    float sigma = sqrtf(s6 / s5);
    float lr = log_radius[0];
    float target = 0.999f / (1.f + expf(-lr));
    s_out[0] = target / (sigma + 1e-8f);
  }
}

// ---------------- phase 1: A = x @ Wx^T + b -> d_out[outs region] ----------------
__global__ __launch_bounds__(256) void k_gemm_xA(
    const float* __restrict__ x, const float* __restrict__ Wx,
    const float* __restrict__ bias, float* __restrict__ Aout) {
  __shared__ short As[128 * 64];
  __shared__ short Bs[128 * 64];
  const int tid = threadIdx.x;
  const int lane = tid & 63;
  const int w = tid >> 6;
  const int n0 = blockIdx.x * 128;
  const int m0 = blockIdx.y * 128;
  const int mq = (w >> 1) * 64;
  const int nq = (w & 1) * 64;

  f32x4 acc[4][4];
#pragma unroll
  for (int i = 0; i < 4; ++i)
#pragma unroll
    for (int j = 0; j < 4; ++j) acc[i][j] = (f32x4){0.f, 0.f, 0.f, 0.f};

  const int r0 = tid >> 3;
  const int c8 = tid & 7;

  for (int k0 = 0; k0 < DD; k0 += 64) {
    __syncthreads();
#pragma unroll
    for (int c = 0; c < 4; ++c) {
      int row = c * 32 + r0;
      const float4* gx = (const float4*)(x + (size_t)(m0 + row) * DD + k0 + c8 * 8);
      const float4* gw = (const float4*)(Wx + (size_t)(n0 + row) * DD + k0 + c8 * 8);
      float4 x0 = gx[0], x1 = gx[1];
      float4 w0 = gw[0], w1 = gw[1];
      short8 xv, wv;
      xv[0]=f2bf(x0.x); xv[1]=f2bf(x0.y); xv[2]=f2bf(x0.z); xv[3]=f2bf(x0.w);
      xv[4]=f2bf(x1.x); xv[5]=f2bf(x1.y); xv[6]=f2bf(x1.z); xv[7]=f2bf(x1.w);
      wv[0]=f2bf(w0.x); wv[1]=f2bf(w0.y); wv[2]=f2bf(w0.z); wv[3]=f2bf(w0.w);
      wv[4]=f2bf(w1.x); wv[5]=f2bf(w1.y); wv[6]=f2bf(w1.z); wv[7]=f2bf(w1.w);
      int so = (row * 64 + c8 * 8) ^ ((row & 7) << 3);
      *(short8*)&As[so] = xv;
      *(short8*)&Bs[so] = wv;
    }
    __syncthreads();
#pragma unroll
    for (int kk = 0; kk < 64; kk += 32) {
      short8 af[4], bfr[4];
#pragma unroll
      for (int f = 0; f < 4; ++f) {
        int ar = mq + f * 16 + (lane & 15);
        int k = kk + ((lane >> 4) << 3);
        af[f] = *(const short8*)&As[(ar * 64 + k) ^ ((ar & 7) << 3)];
        int br = nq + f * 16 + (lane & 15);
        bfr[f] = *(const short8*)&Bs[(br * 64 + k) ^ ((br & 7) << 3)];
      }
#pragma unroll
      for (int i = 0; i < 4; ++i)
#pragma unroll
        for (int j = 0; j < 4; ++j)
          acc[i][j] = __builtin_amdgcn_mfma_f32_16x16x32_bf16(af[i], bfr[j], acc[i][j], 0, 0, 0);
    }
  }
#pragma unroll
  for (int i = 0; i < 4; ++i) {
    int rbase = m0 + mq + i * 16 + ((lane >> 4) << 2);
#pragma unroll
    for (int j = 0; j < 4; ++j) {
      int col = n0 + nq + j * 16 + (lane & 15);
      float bv = bias[col];
#pragma unroll
      for (int r = 0; r < 4; ++r)
        Aout[(size_t)(rbase + r) * DD + col] = acc[i][j][r] + bv;
    }
  }
}

// ---------------- phase 2: recurrence, 384 WGs, single-writer flag barrier ----------------
// WG (nb, mq): rows 16*mq..+15, features 16*nb..+15, full K=1536.
// Barrier: flag[mq*96+nb] = generation (single writer, coherent dword store; NO atomics).
// Consumer: threads 0..95 each spin on one producer flag (monotonic) then __syncthreads.
// h exchange stays coherent (sc0 sc1) / fence-free as validated in R3/R4.
__global__ __launch_bounds__(256) void k_recur(
    const float* __restrict__ Wh, const float* __restrict__ h0,
    const float* __restrict__ z, const float* __restrict__ sp,
    float* __restrict__ outs, float* __restrict__ hall,
    short* __restrict__ hb0, short* __restrict__ hb1, int* __restrict__ flags) {
  __shared__ short WhS[16 * DD];   // 48 KB
  __shared__ f32x4 REDS[4 * 64];   // 4 KB
  const int tid = threadIdx.x;
  const int lane = tid & 63;
  const int wv = tid >> 6;
  const int wgid = blockIdx.x;
  const int nb = wgid >> 2;
  const int mq = wgid & 3;
  const int n0 = nb * 16;
  const int m0 = mq * 16;

  // per-thread geometry
  const int arow = lane & 15;              // A row within tile / B feature col
  const int hi8 = (lane >> 4) << 3;        // k-octet within 32-wide k-step
  const int kw = wv * 384;                 // wave's K-slice base
  const int bbase = arow * DD;             // B (WhS) row base, shorts
  const int bSwz = (lane & 7) << 3;        // swizzle for B reads
  const int r = tid >> 4;                  // epilogue: output row 0..15
  const int c = tid & 15;                  // epilogue: output col 0..15
  const int l2 = ((r >> 2) << 4) | c;      // lane holding (r,c) partial
  const int ri = r & 3;                    // reg index within f32x4
  const size_t eidx = (size_t)(m0 + r) * DD + (n0 + c);     // element in [B,D]
  const size_t aoff = (size_t)(m0 + arow) * DD + kw + hi8;  // A-load base, shorts

  int* myflag = flags + mq * 96 + nb;      // single writer: this WG's tid0
  int* grpflags = flags + mq * 96;         // the 96 producer flags this WG consumes

  // stage Wh rows n0..n0+15 -> LDS bf16, XOR-swizzled
#pragma unroll
  for (int cl = 0; cl < 12; ++cl) {
    int idx = cl * 256 + tid;          // 0..3071
    int row = idx / 192;
    int cc = idx - row * 192;
    const float4* g = (const float4*)(Wh + (size_t)(n0 + row) * DD + cc * 8);
    float4 a0 = g[0], a1 = g[1];
    short8 v;
    v[0]=f2bf(a0.x); v[1]=f2bf(a0.y); v[2]=f2bf(a0.z); v[3]=f2bf(a0.w);
    v[4]=f2bf(a1.x); v[5]=f2bf(a1.y); v[6]=f2bf(a1.z); v[7]=f2bf(a1.w);
    int so = (row * DD + cc * 8) ^ ((row & 7) << 3);
    *(short8*)&WhS[so] = v;
  }

  // init: each WG initializes ITS OWN 16x16 tile of h0 (tiles partition [B,D])
  {
    float v = h0[eidx];
    hall[eidx] = v;                                     // h_all[0]
    st_coh_b16(hb0 + eidx, (unsigned)(unsigned short)f2bf(v));
  }
  const float sv = sp[0];

  // release init writes: gen 1
  asm volatile("s_waitcnt vmcnt(0)" ::: "memory");
  __syncthreads();
  if (tid == 0) st_coh_b32(myflag, 1);
  if (tid < 96) {
    while (__hip_atomic_load(&grpflags[tid], __ATOMIC_RELAXED, __HIP_MEMORY_SCOPE_AGENT) < 1)
      __builtin_amdgcn_s_sleep(1);
  }
  __syncthreads();

  // prefetch A, z for t = 0 (plain cached)
  float pa = outs[eidx];
  float pz = z[eidx];

  for (int t = 0; t < TT; ++t) {
    const short* Hg = (t & 1) ? hb1 : hb0;
    short* Hn = (t & 1) ? hb0 : hb1;
    const short* hp = Hg + aoff;

    // burst 12 coherent 16B A-loads (whole wave K-slice)
    short8 a0,a1,a2,a3,a4,a5,a6,a7,a8,a9,a10,a11;
    LD_COH_B128(a0,  hp, 0);
    LD_COH_B128(a1,  hp, 64);
    LD_COH_B128(a2,  hp, 128);
    LD_COH_B128(a3,  hp, 192);
    LD_COH_B128(a4,  hp, 256);
    LD_COH_B128(a5,  hp, 320);
    LD_COH_B128(a6,  hp, 384);
    LD_COH_B128(a7,  hp, 448);
    LD_COH_B128(a8,  hp, 512);
    LD_COH_B128(a9,  hp, 576);
    LD_COH_B128(a10, hp, 640);
    LD_COH_B128(a11, hp, 704);
    asm volatile("s_waitcnt vmcnt(0)" ::: "memory");
    __builtin_amdgcn_sched_barrier(0);

    f32x4 acc0 = (f32x4){0,0,0,0}, acc1 = (f32x4){0,0,0,0};
#define BFR(j) (*(const short8*)&WhS[(bbase + kw + (j)*32 + hi8) ^ bSwz])
    acc0 = __builtin_amdgcn_mfma_f32_16x16x32_bf16(a0,  BFR(0),  acc0, 0, 0, 0);
    acc1 = __builtin_amdgcn_mfma_f32_16x16x32_bf16(a1,  BFR(1),  acc1, 0, 0, 0);
    acc0 = __builtin_amdgcn_mfma_f32_16x16x32_bf16(a2,  BFR(2),  acc0, 0, 0, 0);
    acc1 = __builtin_amdgcn_mfma_f32_16x16x32_bf16(a3,  BFR(3),  acc1, 0, 0, 0);
    acc0 = __builtin_amdgcn_mfma_f32_16x16x32_bf16(a4,  BFR(4),  acc0, 0, 0, 0);
    acc1 = __builtin_amdgcn_mfma_f32_16x16x32_bf16(a5,  BFR(5),  acc1, 0, 0, 0);
    acc0 = __builtin_amdgcn_mfma_f32_16x16x32_bf16(a6,  BFR(6),  acc0, 0, 0, 0);
    acc1 = __builtin_amdgcn_mfma_f32_16x16x32_bf16(a7,  BFR(7),  acc1, 0, 0, 0);
    acc0 = __builtin_amdgcn_mfma_f32_16x16x32_bf16(a8,  BFR(8),  acc0, 0, 0, 0);
    acc1 = __builtin_amdgcn_mfma_f32_16x16x32_bf16(a9,  BFR(9),  acc1, 0, 0, 0);
    acc0 = __builtin_amdgcn_mfma_f32_16x16x32_bf16(a10, BFR(10), acc0, 0, 0, 0);
    acc1 = __builtin_amdgcn_mfma_f32_16x16x32_bf16(a11, BFR(11), acc1, 0, 0, 0);
#undef BFR

    // cross-wave K reduce via LDS
    REDS[wv * 64 + lane] = acc0 + acc1;
    __syncthreads();
    f32x4 p0 = REDS[l2], p1 = REDS[64 + l2], p2 = REDS[128 + l2], p3 = REDS[192 + l2];
    float ps = (p0[ri] + p1[ri]) + (p2[ri] + p3[ri]);

    // critical path: h_new + coherent store
    float hv = tanhf(pa + sv * ps);
    st_coh_b16(Hn + eidx, (unsigned)(unsigned short)f2bf(hv));

    const bool last = (t == TT - 1);
    if (!last) {
      asm volatile("s_waitcnt vmcnt(0)" ::: "memory");  // h stores acked at IF (this wave)
      __syncthreads();                                   // ... all waves
      if (tid == 0) st_coh_b32(myflag, t + 2);           // single-writer release
    }

    // off-critical-path tail (overlaps the spin)
    size_t tb = (size_t)t * BD;
    hall[tb + BD + eidx] = hv;
    float zz = pz;
    outs[tb + eidx] = hv * (zz / (1.f + __expf(-zz)));
    if (!last) {
      pa = outs[tb + BD + eidx];
      pz = z[tb + BD + eidx];
      int target = t + 2;
      if (tid < 96) {
        while (__hip_atomic_load(&grpflags[tid], __ATOMIC_RELAXED, __HIP_MEMORY_SCOPE_AGENT) < target)
          __builtin_amdgcn_s_sleep(1);
      }
      __syncthreads();
    }
  }
}

// ---------------- launcher ----------------
extern "C" void kernel_launch(void* const* d_in, const int* in_sizes, int n_in,
                              void* d_out, int out_size, void* d_ws, size_t ws_size,
                              hipStream_t stream) {
  const float* x  = (const float*)d_in[0];
  const float* z  = (const float*)d_in[1];
  const float* h0 = (const float*)d_in[2];
  const float* Wx = (const float*)d_in[3];
  const float* Wh = (const float*)d_in[4];
  const float* b  = (const float*)d_in[5];
  const float* lr = (const float*)d_in[6];
  const float* u  = (const float*)d_in[7];

  float* outs = (float*)d_out;
  float* hall = outs + (size_t)TBD;

  char* ws = (char*)d_ws;
  float* vA = (float*)ws;
  float* vB = vA + DD;
  float* vC = vB + DD;
  float* vD = vC + DD;
  float* sS = vD + DD;
  int*   flags = (int*)(ws + 16384);      // 384 single-writer flags (1.5 KB)
  short* hb0 = (short*)(ws + 32768);
  short* hb1 = hb0 + BD;

  // phase 1: big GEMM (independent; enqueue first)
  hipLaunchKernelGGL(k_gemm_xA, dim3(12, 256), dim3(256), 0, stream, x, Wx, b, outs);

  // phase 0: power iteration
  hipMemsetAsync(vA, 0, DD * sizeof(float), stream);
  hipLaunchKernelGGL(k_matvec_col, dim3(6, 8), dim3(256), 0, stream, Wh, u, vA);
  hipLaunchKernelGGL(k_matvec_row, dim3(384), dim3(256), 0, stream, Wh, vA, vB);
  hipMemsetAsync(vA, 0, DD * sizeof(float), stream);
  hipLaunchKernelGGL(k_matvec_col, dim3(6, 8), dim3(256), 0, stream, Wh, vB, vA);
  hipLaunchKernelGGL(k_matvec_row, dim3(384), dim3(256), 0, stream, Wh, vA, vB);
  hipMemsetAsync(vC, 0, DD * sizeof(float), stream);
  hipLaunchKernelGGL(k_matvec_col, dim3(6, 8), dim3(256), 0, stream, Wh, vB, vC);
  hipLaunchKernelGGL(k_matvec_row, dim3(384), dim3(256), 0, stream, Wh, vC, vD);
  hipLaunchKernelGGL(k_scale, dim3(1), dim3(256), 0, stream, vC, vD, lr, sS);

  // zero the flag array (graph-capture-safe, per-launch)
  hipMemsetAsync(flags, 0, NWG * sizeof(int), stream);

  // phase 2: cooperative launch (co-residency guaranteed)
  void* args[9] = {(void*)&Wh, (void*)&h0, (void*)&z, (void*)&sS,
                   (void*)&outs, (void*)&hall, (void*)&hb0, (void*)&hb1, (void*)&flags};
  hipLaunchCooperativeKernel((const void*)k_recur, dim3(NWG), dim3(256), args, 0, stream);
}

// Round 6
// 3046.501 us; speedup vs baseline: 5.6881x; 1.2768x over previous
//
#include <hip/hip_runtime.h>

#define DD 1536
#define TT 512
#define BB 64
#define BD (BB*DD)      /* 98304 */
#define TBD (TT*BD)     /* 50331648 */
#define NWG 96          /* 24 feature-groups x 4 batch-quadrants */

typedef __attribute__((ext_vector_type(8))) short short8;
typedef __attribute__((ext_vector_type(4))) float f32x4;
typedef unsigned long long u64;

__device__ __forceinline__ short f2bf(float f) {
  unsigned u = __builtin_bit_cast(unsigned, f);
  u += 0x7FFFu + ((u >> 16) & 1u);   // RNE
  return (short)(u >> 16);
}

// coherent (device-scope, L1/L2-bypassing) stores -> Infinity Cache
__device__ __forceinline__ void st_coh_b32(int* p, int v) {
  asm volatile("global_store_dword %0, %1, off sc0 sc1" :: "v"(p), "v"(v) : "memory");
}

// coherent 16B load from Infinity Cache (bypasses L1/L2)
#define LD_COH_B128(dst, addr, imm) \
  asm volatile("global_load_dwordx4 %0, %1, off offset:" #imm " sc0 sc1" \
               : "=v"(dst) : "v"(addr) : "memory")

// ---------------- power iteration helpers (f32 exact) ----------------

__global__ __launch_bounds__(256) void k_matvec_row(
    const float* __restrict__ W, const float* __restrict__ x, float* __restrict__ y) {
  int wave = (blockIdx.x * 256 + threadIdx.x) >> 6;
  int lane = threadIdx.x & 63;
  const float* Wr = W + (size_t)wave * DD;
  float acc = 0.f;
  for (int j = lane; j < DD; j += 64) acc += Wr[j] * x[j];
  for (int off = 32; off; off >>= 1) acc += __shfl_down(acc, off, 64);
  if (lane == 0) y[wave] = acc;
}

__global__ __launch_bounds__(256) void k_matvec_col(
    const float* __restrict__ W, const float* __restrict__ x, float* __restrict__ y) {
  int j = blockIdx.x * 256 + threadIdx.x;
  int i0 = blockIdx.y * 192;
  float acc = 0.f;
  for (int i = i0; i < i0 + 192; ++i) acc += W[(size_t)i * DD + j] * x[i];
  atomicAdd(&y[j], acc);
}

__global__ __launch_bounds__(256) void k_scale(
    const float* __restrict__ t5, const float* __restrict__ t6,
    const float* __restrict__ log_radius, float* __restrict__ s_out) {
  __shared__ float red[8];
  int tid = threadIdx.x;
  float a5 = 0.f, a6 = 0.f;
  for (int i = tid; i < DD; i += 256) { float v5 = t5[i], v6 = t6[i]; a5 += v5*v5; a6 += v6*v6; }
  for (int off = 32; off; off >>= 1) { a5 += __shfl_down(a5, off, 64); a6 += __shfl_down(a6, off, 64); }
  int w = tid >> 6, lane = tid & 63;
  if (lane == 0) { red[w] = a5; red[4 + w] = a6; }
  __syncthreads();
  if (tid == 0) {
    float s5 = red[0] + red[1] + red[2] + red[3];
    float s6 = red[4] + red[5] + red[6] + red[7];
    float sigma = sqrtf(s6 / s5);
    float lr = log_radius[0];
    float target = 0.999f / (1.f + expf(-lr));
    s_out[0] = target / (sigma + 1e-8f);
  }
}

// ---------------- phase 1: A = x @ Wx^T + b -> d_out[outs region] ----------------
__global__ __launch_bounds__(256) void k_gemm_xA(
    const float* __restrict__ x, const float* __restrict__ Wx,
    const float* __restrict__ bias, float* __restrict__ Aout) {
  __shared__ short As[128 * 64];
  __shared__ short Bs[128 * 64];
  const int tid = threadIdx.x;
  const int lane = tid & 63;
  const int w = tid >> 6;
  const int n0 = blockIdx.x * 128;
  const int m0 = blockIdx.y * 128;
  const int mq = (w >> 1) * 64;
  const int nq = (w & 1) * 64;

  f32x4 acc[4][4];
#pragma unroll
  for (int i = 0; i < 4; ++i)
#pragma unroll
    for (int j = 0; j < 4; ++j) acc[i][j] = (f32x4){0.f, 0.f, 0.f, 0.f};

  const int r0 = tid >> 3;
  const int c8 = tid & 7;

  for (int k0 = 0; k0 < DD; k0 += 64) {
    __syncthreads();
#pragma unroll
    for (int c = 0; c < 4; ++c) {
      int row = c * 32 + r0;
      const float4* gx = (const float4*)(x + (size_t)(m0 + row) * DD + k0 + c8 * 8);
      const float4* gw = (const float4*)(Wx + (size_t)(n0 + row) * DD + k0 + c8 * 8);
      float4 x0 = gx[0], x1 = gx[1];
      float4 w0 = gw[0], w1 = gw[1];
      short8 xv, wv;
      xv[0]=f2bf(x0.x); xv[1]=f2bf(x0.y); xv[2]=f2bf(x0.z); xv[3]=f2bf(x0.w);
      xv[4]=f2bf(x1.x); xv[5]=f2bf(x1.y); xv[6]=f2bf(x1.z); xv[7]=f2bf(x1.w);
      wv[0]=f2bf(w0.x); wv[1]=f2bf(w0.y); wv[2]=f2bf(w0.z); wv[3]=f2bf(w0.w);
      wv[4]=f2bf(w1.x); wv[5]=f2bf(w1.y); wv[6]=f2bf(w1.z); wv[7]=f2bf(w1.w);
      int so = (row * 64 + c8 * 8) ^ ((row & 7) << 3);
      *(short8*)&As[so] = xv;
      *(short8*)&Bs[so] = wv;
    }
    __syncthreads();
#pragma unroll
    for (int kk = 0; kk < 64; kk += 32) {
      short8 af[4], bfr[4];
#pragma unroll
      for (int f = 0; f < 4; ++f) {
        int ar = mq + f * 16 + (lane & 15);
        int k = kk + ((lane >> 4) << 3);
        af[f] = *(const short8*)&As[(ar * 64 + k) ^ ((ar & 7) << 3)];
        int br = nq + f * 16 + (lane & 15);
        bfr[f] = *(const short8*)&Bs[(br * 64 + k) ^ ((br & 7) << 3)];
      }
#pragma unroll
      for (int i = 0; i < 4; ++i)
#pragma unroll
        for (int j = 0; j < 4; ++j)
          acc[i][j] = __builtin_amdgcn_mfma_f32_16x16x32_bf16(af[i], bfr[j], acc[i][j], 0, 0, 0);
    }
  }
#pragma unroll
  for (int i = 0; i < 4; ++i) {
    int rbase = m0 + mq + i * 16 + ((lane >> 4) << 2);
#pragma unroll
    for (int j = 0; j < 4; ++j) {
      int col = n0 + nq + j * 16 + (lane & 15);
      float bv = bias[col];
#pragma unroll
      for (int r = 0; r < 4; ++r)
        Aout[(size_t)(rbase + r) * DD + col] = acc[i][j][r] + bv;
    }
  }
}

// ---------------- phase 2: recurrence, 96 WGs x 512 thr, Wh in registers ----------------
// WG (fg, mq): rows 16*mq..+15, features 64*fg..+63, full K=1536 split over 8 waves.
// Wh tile lives in VGPRs (24 short8 frags/lane). Per-wave spin on its 3 K-slice
// producers (early start); in-WG reduce __syncthreads gates h-writes on all 24
// producers -> 2-buffer ping-pong stays race-free (reads complete before flag).
__global__ __launch_bounds__(512, 2) void k_recur(
    const float* __restrict__ Wh, const float* __restrict__ h0,
    const float* __restrict__ z, const float* __restrict__ sp,
    float* __restrict__ outs, float* __restrict__ hall,
    short* __restrict__ hb0, short* __restrict__ hb1, int* __restrict__ flags) {
  __shared__ f32x4 REDS[2048];     // [8 waves][4 fcols][64 lanes] = 32 KB
  const int tid = threadIdx.x;
  const int lane = tid & 63;
  const int wv = tid >> 6;         // 0..7
  const int wgid = blockIdx.x;     // 0..95
  const int fg = wgid >> 2;        // 0..23
  const int mq = wgid & 3;
  const int n0 = fg * 64;
  const int m0 = mq * 16;

  const int nl = lane & 15;
  const int hi8 = (lane >> 4) << 3;
  const int kw = wv * 192;         // wave's K-slice base

  // ---- one-time: Wh tile -> registers (f32 -> bf16) ----
  short8 bfr[6][4];
#pragma unroll
  for (int j = 0; j < 6; ++j)
#pragma unroll
    for (int f = 0; f < 4; ++f) {
      const float* gp = Wh + (size_t)(n0 + f * 16 + nl) * DD + kw + j * 32 + hi8;
      float4 a0 = *(const float4*)gp;
      float4 a1 = *(const float4*)(gp + 4);
      short8 v;
      v[0]=f2bf(a0.x); v[1]=f2bf(a0.y); v[2]=f2bf(a0.z); v[3]=f2bf(a0.w);
      v[4]=f2bf(a1.x); v[5]=f2bf(a1.y); v[6]=f2bf(a1.z); v[7]=f2bf(a1.w);
      bfr[j][f] = v;
    }

  // epilogue geometry: 2 consecutive outputs per thread
  const int o = tid * 2;
  const int r = o >> 6;            // 0..15
  const int c = o & 63;            // even
  const int f0 = c >> 4;
  const int c15 = c & 15;
  const int l2a = ((r >> 2) << 4) | c15;
  const int l2b = l2a + 1;
  const int ri = r & 3;
  const size_t eidx = (size_t)(m0 + r) * DD + n0 + c;       // element in [B,D]
  const size_t aoff = (size_t)(m0 + nl) * DD + kw + hi8;    // A-load base, shorts

  int* myflag = flags + mq * 24 + fg;
  const int pf = mq * 24 + wv * 3;   // this wave's 3 producer flags

  // init own tile: hall[0] = h0 (f32), hb0 = bf16(h0) coherent packed
  {
    float vx = h0[eidx], vy = h0[eidx + 1];
    hall[eidx] = vx; hall[eidx + 1] = vy;
    unsigned pk = (unsigned)(unsigned short)f2bf(vx)
                | ((unsigned)(unsigned short)f2bf(vy) << 16);
    st_coh_b32((int*)(hb0 + eidx), (int)pk);
  }
  const float sv = sp[0];
  asm volatile("s_waitcnt vmcnt(0)" ::: "memory");
  __syncthreads();
  if (tid == 0) st_coh_b32(myflag, 1);

  // prefetch A, z for t = 0 (plain cached)
  float pax = outs[eidx], pay = outs[eidx + 1];
  float pzx = z[eidx], pzy = z[eidx + 1];

  for (int t = 0; t < TT; ++t) {
    const short* Hg = (t & 1) ? hb1 : hb0;
    short* Hn = (t & 1) ? hb0 : hb1;

    // per-wave wait: the 3 producer WGs covering this wave's K-slice
    if (lane < 3) {
      while (__hip_atomic_load(&flags[pf + lane], __ATOMIC_RELAXED, __HIP_MEMORY_SCOPE_AGENT) < t + 1)
        __builtin_amdgcn_s_sleep(1);
    }

    // burst 6 coherent 16B A-loads (wave's 192-k slice of 16 rows)
    const short* hp = Hg + aoff;
    short8 a0, a1, a2, a3, a4, a5;
    LD_COH_B128(a0, hp, 0);
    LD_COH_B128(a1, hp, 64);
    LD_COH_B128(a2, hp, 128);
    LD_COH_B128(a3, hp, 192);
    LD_COH_B128(a4, hp, 256);
    LD_COH_B128(a5, hp, 320);
    asm volatile("s_waitcnt vmcnt(0)" ::: "memory");
    __builtin_amdgcn_sched_barrier(0);

    f32x4 acc0 = (f32x4){0,0,0,0}, acc1 = (f32x4){0,0,0,0};
    f32x4 acc2 = (f32x4){0,0,0,0}, acc3 = (f32x4){0,0,0,0};
#define MF4(aa, j) \
    acc0 = __builtin_amdgcn_mfma_f32_16x16x32_bf16(aa, bfr[j][0], acc0, 0, 0, 0); \
    acc1 = __builtin_amdgcn_mfma_f32_16x16x32_bf16(aa, bfr[j][1], acc1, 0, 0, 0); \
    acc2 = __builtin_amdgcn_mfma_f32_16x16x32_bf16(aa, bfr[j][2], acc2, 0, 0, 0); \
    acc3 = __builtin_amdgcn_mfma_f32_16x16x32_bf16(aa, bfr[j][3], acc3, 0, 0, 0);
    MF4(a0, 0) MF4(a1, 1) MF4(a2, 2) MF4(a3, 3) MF4(a4, 4) MF4(a5, 5)
#undef MF4

    // cross-wave K reduce via LDS
    REDS[wv * 256 + 0 * 64 + lane] = acc0;
    REDS[wv * 256 + 1 * 64 + lane] = acc1;
    REDS[wv * 256 + 2 * 64 + lane] = acc2;
    REDS[wv * 256 + 3 * 64 + lane] = acc3;
    __syncthreads();
    float s0 = 0.f, s1 = 0.f;
#pragma unroll
    for (int w2 = 0; w2 < 8; ++w2) {
      s0 += REDS[w2 * 256 + f0 * 64 + l2a][ri];
      s1 += REDS[w2 * 256 + f0 * 64 + l2b][ri];
    }

    // critical path: h_new + coherent packed store
    float h0v = tanhf(pax + sv * s0);
    float h1v = tanhf(pay + sv * s1);
    unsigned pk = (unsigned)(unsigned short)f2bf(h0v)
                | ((unsigned)(unsigned short)f2bf(h1v) << 16);
    st_coh_b32((int*)(Hn + eidx), (int)pk);

    const bool last = (t == TT - 1);
    if (!last) {
      asm volatile("s_waitcnt vmcnt(0)" ::: "memory");  // h stores acked at IF
      __syncthreads();                                   // all waves (also protects REDS)
      if (tid == 0) st_coh_b32(myflag, t + 2);           // single-writer release
    }

    // off-critical-path tail (overlaps consumers' spins)
    size_t tb = (size_t)t * BD;
    hall[tb + BD + eidx] = h0v;
    hall[tb + BD + eidx + 1] = h1v;
    outs[tb + eidx]     = h0v * (pzx / (1.f + __expf(-pzx)));
    outs[tb + eidx + 1] = h1v * (pzy / (1.f + __expf(-pzy)));
    if (!last) {
      pax = outs[tb + BD + eidx]; pay = outs[tb + BD + eidx + 1];
      pzx = z[tb + BD + eidx];    pzy = z[tb + BD + eidx + 1];
    }
  }
}

// ---------------- launcher ----------------
extern "C" void kernel_launch(void* const* d_in, const int* in_sizes, int n_in,
                              void* d_out, int out_size, void* d_ws, size_t ws_size,
                              hipStream_t stream) {
  const float* x  = (const float*)d_in[0];
  const float* z  = (const float*)d_in[1];
  const float* h0 = (const float*)d_in[2];
  const float* Wx = (const float*)d_in[3];
  const float* Wh = (const float*)d_in[4];
  const float* b  = (const float*)d_in[5];
  const float* lr = (const float*)d_in[6];
  const float* u  = (const float*)d_in[7];

  float* outs = (float*)d_out;
  float* hall = outs + (size_t)TBD;

  char* ws = (char*)d_ws;
  float* vA = (float*)ws;
  float* vB = vA + DD;
  float* vC = vB + DD;
  float* vD = vC + DD;
  float* sS = vD + DD;
  int*   flags = (int*)(ws + 16384);      // 96 single-writer flags
  short* hb0 = (short*)(ws + 32768);
  short* hb1 = hb0 + BD;

  // phase 1: big GEMM (independent; enqueue first)
  hipLaunchKernelGGL(k_gemm_xA, dim3(12, 256), dim3(256), 0, stream, x, Wx, b, outs);

  // phase 0: power iteration
  hipMemsetAsync(vA, 0, DD * sizeof(float), stream);
  hipLaunchKernelGGL(k_matvec_col, dim3(6, 8), dim3(256), 0, stream, Wh, u, vA);
  hipLaunchKernelGGL(k_matvec_row, dim3(384), dim3(256), 0, stream, Wh, vA, vB);
  hipMemsetAsync(vA, 0, DD * sizeof(float), stream);
  hipLaunchKernelGGL(k_matvec_col, dim3(6, 8), dim3(256), 0, stream, Wh, vB, vA);
  hipLaunchKernelGGL(k_matvec_row, dim3(384), dim3(256), 0, stream, Wh, vA, vB);
  hipMemsetAsync(vC, 0, DD * sizeof(float), stream);
  hipLaunchKernelGGL(k_matvec_col, dim3(6, 8), dim3(256), 0, stream, Wh, vB, vC);
  hipLaunchKernelGGL(k_matvec_row, dim3(384), dim3(256), 0, stream, Wh, vC, vD);
  hipLaunchKernelGGL(k_scale, dim3(1), dim3(256), 0, stream, vC, vD, lr, sS);

  // zero the flag array (graph-capture-safe, per-launch)
  hipMemsetAsync(flags, 0, 1024, stream);

  // phase 2: cooperative launch (co-residency guaranteed)
  void* args[9] = {(void*)&Wh, (void*)&h0, (void*)&z, (void*)&sS,
                   (void*)&outs, (void*)&hall, (void*)&hb0, (void*)&hb1, (void*)&flags};
  hipLaunchCooperativeKernel((const void*)k_recur, dim3(NWG), dim3(512), args, 0, stream);
}